// Round 1
// baseline (1338.609 us; speedup 1.0000x reference)
//
#include <hip/hip_runtime.h>
#include <math.h>

#define HW 4096

__device__ __forceinline__ void fma4(float4& a, float s, float4 b) {
  a.x = fmaf(s, b.x, a.x);
  a.y = fmaf(s, b.y, a.y);
  a.z = fmaf(s, b.z, a.z);
  a.w = fmaf(s, b.w, a.w);
}

// ---------------------------------------------------------------------------
// kv projection: kv = s @ W^T + b for both halves of x_skip.
// Outputs K1t,V1t,K2t,V2t all in (b, 64, 4096) channel-major layout so that
// all downstream loads are coalesced along n.
// grid (64 nblk, 8 b), block 256
// ---------------------------------------------------------------------------
__global__ __launch_bounds__(256) void kv_proj(
    const float* __restrict__ xs,
    const float* __restrict__ w1, const float* __restrict__ b1,
    const float* __restrict__ w2, const float* __restrict__ b2,
    float* __restrict__ K1t, float* __restrict__ V1t,
    float* __restrict__ K2t, float* __restrict__ V2t) {
  __shared__ float Ss[64][65];    // [ch][n]  pad 65 -> conflict-free
  __shared__ float Ws[128 * 64];  // weights of current branch
  const int b = blockIdx.y, n0 = blockIdx.x * 64;
  const int t = threadIdx.x;
  const int lane_n = t & 63, jg = t >> 6;  // jg in 0..3
  const int jbase = jg * 32;
  const float* xsb = xs + (size_t)b * 128 * HW;

  for (int br = 0; br < 2; ++br) {
    const float* W = br ? w2 : w1;
    const float* bias = br ? b2 : b1;
    const float* src = xsb + (br ? 64 * HW : 0);
    float* Kt = (br ? K2t : K1t) + (size_t)b * 64 * HW;
    float* Vt = (br ? V2t : V1t) + (size_t)b * 64 * HW;
    __syncthreads();
    // stage s tile (64 ch x 64 n), coalesced along n
    for (int s = 0; s < 16; ++s) {
      int ch = s * 4 + jg;
      Ss[ch][lane_n] = src[(size_t)ch * HW + n0 + lane_n];
    }
    for (int i = t; i < 128 * 64; i += 256) Ws[i] = W[i];
    __syncthreads();

    float acc[32];
#pragma unroll
    for (int i = 0; i < 32; ++i) acc[i] = bias[jbase + i];
    for (int ch = 0; ch < 64; ++ch) {
      float s = Ss[ch][lane_n];
#pragma unroll
      for (int i = 0; i < 32; ++i) acc[i] = fmaf(Ws[(jbase + i) * 64 + ch], s, acc[i]);
    }
#pragma unroll
    for (int i = 0; i < 32; ++i) {
      int j = jbase + i;
      float* dst = (j < 64) ? (Kt + (size_t)j * HW) : (Vt + (size_t)(j - 64) * HW);
      dst[n0 + lane_n] = acc[i];  // coalesced along n
    }
  }
}

// ---------------------------------------------------------------------------
// Spatial attention (flash-style, online softmax) + shortcut add.
// x_cat[b][ch][n] = sout[n][ch] + x_up[b,ch,n] + x_skip[b,ch,n], ch in [0,64)
// grid (64 qblk, 8 b), block 256. Thread t: q = t>>2 (row), g = t&3,
// columns/channels chunk cb = g*16.
// ---------------------------------------------------------------------------
__global__ __launch_bounds__(256) void attn_spatial(
    const float* __restrict__ xu, const float* __restrict__ xs,
    const float* __restrict__ K1t, const float* __restrict__ V1t,
    float* __restrict__ xcat) {
  __shared__ float Qs[64][65];  // [q][ch]   scalar reads, pad 65
  __shared__ float Ks[64][68];  // [ch][k]   float4 reads, pad 68 (16B aligned)
  __shared__ float Vs[64][68];  // [k][ch]   float4 reads
  const int b = blockIdx.y, q0 = blockIdx.x * 64;
  const int t = threadIdx.x;
  const int lane = t & 63;
  const int q = t >> 2, g = t & 3, cb = g * 16;
  const int qsrc = lane & 60;  // quad base lane for shfl

  const float* xub = xu + (size_t)b * 128 * HW;
  const float* xsb = xs + (size_t)b * 128 * HW;
  const float* Kb = K1t + (size_t)b * 64 * HW;
  const float* Vb = V1t + (size_t)b * 64 * HW;

  // stage Q tile (transpose: global (ch,n) -> LDS (q,ch))
  for (int s = 0; s < 16; ++s) {
    int ch = s * 4 + (t >> 6);
    Qs[lane][ch] = xub[(size_t)ch * HW + q0 + lane];
  }

  float m = -1e30f, l = 0.f;
  float4 O[4];
#pragma unroll
  for (int i = 0; i < 4; ++i) O[i] = make_float4(0.f, 0.f, 0.f, 0.f);

  for (int kb = 0; kb < 64; ++kb) {
    __syncthreads();  // also covers initial Q staging
    const int n0 = kb * 64;
    // K tile: (ch, k), coalesced loads
    for (int s = 0; s < 16; ++s) {
      int ch = s * 4 + (t >> 6);
      Ks[ch][lane] = Kb[(size_t)ch * HW + n0 + lane];
    }
    // V tile transposed to (k, ch); each thread gathers 4 channels for its k
    {
      int k = lane;
      int c0 = (t >> 6) * 4;
      for (int s = 0; s < 4; ++s) {
        int ch0 = s * 16 + c0;
        float4 v;
        v.x = Vb[(size_t)(ch0 + 0) * HW + n0 + k];
        v.y = Vb[(size_t)(ch0 + 1) * HW + n0 + k];
        v.z = Vb[(size_t)(ch0 + 2) * HW + n0 + k];
        v.w = Vb[(size_t)(ch0 + 3) * HW + n0 + k];
        *(float4*)&Vs[k][ch0] = v;
      }
    }
    __syncthreads();

    // S = Q K^T for (row q, cols cb..cb+15); no softmax scale in reference
    float sv[16];
#pragma unroll
    for (int i = 0; i < 16; ++i) sv[i] = 0.f;
    for (int ch = 0; ch < 64; ++ch) {
      float qv = Qs[q][ch];
      const float4* kr = (const float4*)&Ks[ch][cb];
#pragma unroll
      for (int jj = 0; jj < 4; ++jj) {
        float4 k4 = kr[jj];
        sv[jj * 4 + 0] = fmaf(qv, k4.x, sv[jj * 4 + 0]);
        sv[jj * 4 + 1] = fmaf(qv, k4.y, sv[jj * 4 + 1]);
        sv[jj * 4 + 2] = fmaf(qv, k4.z, sv[jj * 4 + 2]);
        sv[jj * 4 + 3] = fmaf(qv, k4.w, sv[jj * 4 + 3]);
      }
    }
    // online softmax stats across the quad (4 lanes own row q)
    float mx = sv[0];
#pragma unroll
    for (int i = 1; i < 16; ++i) mx = fmaxf(mx, sv[i]);
    mx = fmaxf(mx, __shfl_xor(mx, 1));
    mx = fmaxf(mx, __shfl_xor(mx, 2));
    float mnew = fmaxf(m, mx);
    float p[16];
    float psum = 0.f;
#pragma unroll
    for (int i = 0; i < 16; ++i) {
      p[i] = __expf(sv[i] - mnew);
      psum += p[i];
    }
    psum += __shfl_xor(psum, 1);
    psum += __shfl_xor(psum, 2);
    float alpha = __expf(m - mnew);
    l = l * alpha + psum;
    m = mnew;
#pragma unroll
    for (int i = 0; i < 4; ++i) {
      O[i].x *= alpha; O[i].y *= alpha; O[i].z *= alpha; O[i].w *= alpha;
    }
    // O[q][cb..cb+15] += sum_k P[q][k] * V[k][cb..cb+15]; P fetched from quad regs
#pragma unroll
    for (int k = 0; k < 64; ++k) {
      float pv = __shfl(p[k & 15], qsrc | (k >> 4), 64);
      const float4* vr = (const float4*)&Vs[k][cb];
#pragma unroll
      for (int jj = 0; jj < 4; ++jj) fma4(O[jj], pv, vr[jj]);
    }
  }

  // epilogue: normalize + shortcut1, write channel-major
  float invl = 1.f / l;
  float* ob = xcat + (size_t)b * 128 * HW;
  const int n = q0 + q;
#pragma unroll
  for (int jj = 0; jj < 4; ++jj) {
    int ch = cb + jj * 4;
    float4 o = O[jj];
    ob[(size_t)(ch + 0) * HW + n] = o.x * invl + xub[(size_t)(ch + 0) * HW + n] + xsb[(size_t)(ch + 0) * HW + n];
    ob[(size_t)(ch + 1) * HW + n] = o.y * invl + xub[(size_t)(ch + 1) * HW + n] + xsb[(size_t)(ch + 1) * HW + n];
    ob[(size_t)(ch + 2) * HW + n] = o.z * invl + xub[(size_t)(ch + 2) * HW + n] + xsb[(size_t)(ch + 2) * HW + n];
    ob[(size_t)(ch + 3) * HW + n] = o.w * invl + xub[(size_t)(ch + 3) * HW + n] + xsb[(size_t)(ch + 3) * HW + n];
  }
}

// ---------------------------------------------------------------------------
// Channel gram: M[b][c][d] = sum_n u2[n][c] * k2[n][d]
// grid (16 nchunk, 8 b), block 256: c = t&63, dg = t>>6 -> 16 d's each.
// Partial sums over a 256-n chunk, atomically accumulated (M pre-zeroed).
// ---------------------------------------------------------------------------
__global__ __launch_bounds__(256) void chan_gram(
    const float* __restrict__ xu, const float* __restrict__ K2t,
    float* __restrict__ M) {
  const int b = blockIdx.y, n0 = blockIdx.x * 256;
  const int t = threadIdx.x, c = t & 63, dg = t >> 6;
  const float* urow = xu + ((size_t)b * 128 + 64 + c) * HW + n0;
  const float* kbase = K2t + (size_t)b * 64 * HW + n0;
  float acc[16];
#pragma unroll
  for (int i = 0; i < 16; ++i) acc[i] = 0.f;
  for (int n = 0; n < 256; ++n) {
    float u = urow[n];
#pragma unroll
    for (int i = 0; i < 16; ++i)
      acc[i] = fmaf(kbase[(size_t)(dg * 16 + i) * HW + n], u, acc[i]);  // broadcast read
  }
  float* Mb = M + b * 4096;
#pragma unroll
  for (int i = 0; i < 16; ++i) atomicAdd(&Mb[c * 64 + dg * 16 + i], acc[i]);
}

// softmax over c (axis=1) for each (b, d). grid 8, block 64 (lane = d).
__global__ void chan_softmax(const float* __restrict__ M, float* __restrict__ A) {
  const int b = blockIdx.x, d = threadIdx.x;
  const float* Mb = M + b * 4096;
  float* Ab = A + b * 4096;
  float mx = -1e30f;
  for (int c = 0; c < 64; ++c) mx = fmaxf(mx, Mb[c * 64 + d]);
  float s = 0.f;
  for (int c = 0; c < 64; ++c) {
    float e = __expf(Mb[c * 64 + d] - mx);
    Ab[c * 64 + d] = e;
    s += e;
  }
  float inv = 1.f / s;
  for (int c = 0; c < 64; ++c) Ab[c * 64 + d] *= inv;
}

// ---------------------------------------------------------------------------
// cout[n][d] = sum_c v2[n][c] * A[c][d]; + shortcut2; write channels 64..127.
// grid (64 nblk, 8 b), block 256: n = n0 + (t&63), dg = t>>6 -> 16 d's.
// ---------------------------------------------------------------------------
__global__ __launch_bounds__(256) void chan_apply(
    const float* __restrict__ V2t, const float* __restrict__ A,
    const float* __restrict__ xu, const float* __restrict__ xs,
    float* __restrict__ xcat) {
  __shared__ float Vsm[64][65];  // [n][c]
  __shared__ float As[64][65];   // [c][d]
  const int b = blockIdx.y, n0 = blockIdx.x * 64, t = threadIdx.x;
  const int lane = t & 63, dg = t >> 6;
  const float* Vb = V2t + (size_t)b * 64 * HW;
  for (int s = 0; s < 16; ++s) {
    int c = s * 4 + dg;
    Vsm[lane][c] = Vb[(size_t)c * HW + n0 + lane];  // coalesced, transposed store
  }
  for (int idx = t; idx < 4096; idx += 256) As[idx >> 6][idx & 63] = A[b * 4096 + idx];
  __syncthreads();

  float acc[16];
#pragma unroll
  for (int i = 0; i < 16; ++i) acc[i] = 0.f;
  for (int c = 0; c < 64; ++c) {
    float v = Vsm[lane][c];
#pragma unroll
    for (int i = 0; i < 16; ++i) acc[i] = fmaf(v, As[c][dg * 16 + i], acc[i]);
  }
  const float* xub = xu + ((size_t)b * 128 + 64) * HW;
  const float* xsb = xs + ((size_t)b * 128 + 64) * HW;
  float* ob = xcat + ((size_t)b * 128 + 64) * HW;
  const int n = n0 + lane;
#pragma unroll
  for (int i = 0; i < 16; ++i) {
    int d = dg * 16 + i;
    ob[(size_t)d * HW + n] = acc[i] + xub[(size_t)d * HW + n] + xsb[(size_t)d * HW + n];
  }
}

// ---------------------------------------------------------------------------
// Direct 3x3 SAME conv + BN + ReLU.
// grid (16 rowblk, 8 ocblk, 8 b), block 256.
// Thread: oc = oc0 + (t>>4), 4 rows x 4 cols at w0 = (t&15)*4.
// ---------------------------------------------------------------------------
__global__ __launch_bounds__(256) void conv_bn_relu(
    const float* __restrict__ x, const float* __restrict__ cw,
    const float* __restrict__ gamma, const float* __restrict__ beta,
    const float* __restrict__ mean, const float* __restrict__ var,
    float* __restrict__ out) {
  __shared__ float In[8][6][68];   // 8 ic x (4+2 halo rows) x (66 cols + pad)
  __shared__ float Wt[16 * 8 * 9];
  const int b = blockIdx.z, oc0 = blockIdx.y * 16, r0 = blockIdx.x * 4;
  const int t = threadIdx.x;
  const int ocl = t >> 4, oc = oc0 + ocl, wg = t & 15, w0 = wg * 4;
  const float* xb = x + (size_t)b * 128 * HW;

  float acc[4][4];
#pragma unroll
  for (int r = 0; r < 4; ++r)
#pragma unroll
    for (int j = 0; j < 4; ++j) acc[r][j] = 0.f;

  for (int icb = 0; icb < 128; icb += 8) {
    __syncthreads();
    for (int idx = t; idx < 8 * 6 * 68; idx += 256) {
      int ic = idx / 408;
      int rem = idx - ic * 408;
      int ir = rem / 68;
      int col = rem - ir * 68;
      int h = r0 - 1 + ir;
      int w = col - 1;
      float v = 0.f;
      if (col < 66 && (unsigned)h < 64u && (unsigned)w < 64u)
        v = xb[(size_t)(icb + ic) * HW + h * 64 + w];
      In[ic][ir][col] = v;
    }
    for (int idx = t; idx < 16 * 8 * 9; idx += 256) {
      int o = idx / 72;
      int rem = idx - o * 72;  // ic*9 + tap
      Wt[idx] = cw[((size_t)(oc0 + o) * 128 + icb) * 9 + rem];
    }
    __syncthreads();

    for (int ic = 0; ic < 8; ++ic) {
      float wreg[9];
#pragma unroll
      for (int i = 0; i < 9; ++i) wreg[i] = Wt[(ocl * 8 + ic) * 9 + i];
#pragma unroll
      for (int ir = 0; ir < 6; ++ir) {
        float4 a4 = *(const float4*)&In[ic][ir][w0];
        float2 b2 = *(const float2*)&In[ic][ir][w0 + 4];
        float iv[6] = {a4.x, a4.y, a4.z, a4.w, b2.x, b2.y};
        int rlo = ir - 2 < 0 ? 0 : ir - 2;
        int rhi = ir < 3 ? ir : 3;
#pragma unroll
        for (int r = 0; r < 4; ++r) {
          if (r < rlo || r > rhi) continue;  // constant-folded after ir unroll
          int dh = ir - r;
#pragma unroll
          for (int dw = 0; dw < 3; ++dw) {
            float wv = wreg[dh * 3 + dw];
            acc[r][0] = fmaf(wv, iv[dw + 0], acc[r][0]);
            acc[r][1] = fmaf(wv, iv[dw + 1], acc[r][1]);
            acc[r][2] = fmaf(wv, iv[dw + 2], acc[r][2]);
            acc[r][3] = fmaf(wv, iv[dw + 3], acc[r][3]);
          }
        }
      }
    }
  }

  float inv = rsqrtf(var[oc] + 1e-5f);
  float sc = inv * gamma[oc];
  float sh = beta[oc] - mean[oc] * sc;
  float* ob = out + ((size_t)b * 128 + oc) * HW + r0 * 64 + w0;
#pragma unroll
  for (int r = 0; r < 4; ++r) {
    float4 v;
    v.x = fmaxf(fmaf(acc[r][0], sc, sh), 0.f);
    v.y = fmaxf(fmaf(acc[r][1], sc, sh), 0.f);
    v.z = fmaxf(fmaf(acc[r][2], sc, sh), 0.f);
    v.w = fmaxf(fmaf(acc[r][3], sc, sh), 0.f);
    *(float4*)&ob[r * 64] = v;
  }
}

// ---------------------------------------------------------------------------
extern "C" void kernel_launch(void* const* d_in, const int* in_sizes, int n_in,
                              void* d_out, int out_size, void* d_ws, size_t ws_size,
                              hipStream_t stream) {
  const float* x_up   = (const float*)d_in[0];
  const float* x_skip = (const float*)d_in[1];
  const float* kv1_w  = (const float*)d_in[2];
  const float* kv1_b  = (const float*)d_in[3];
  const float* kv2_w  = (const float*)d_in[4];
  const float* kv2_b  = (const float*)d_in[5];
  const float* conv_w = (const float*)d_in[6];
  const float* bn_g   = (const float*)d_in[7];
  const float* bn_b   = (const float*)d_in[8];
  const float* bn_m   = (const float*)d_in[9];
  const float* bn_v   = (const float*)d_in[10];
  float* out = (float*)d_out;

  char* ws = (char*)d_ws;
  const size_t XCAT_B = (size_t)8 * 128 * HW * 4;  // 16.78 MB
  const size_t KV_B   = (size_t)8 * 64 * HW * 4;   // 8.39 MB each
  float* xcat = (float*)ws;
  float* K1t  = (float*)(ws + XCAT_B);
  float* V1t  = (float*)(ws + XCAT_B + KV_B);
  float* K2t  = (float*)(ws + XCAT_B + 2 * KV_B);
  float* V2t  = (float*)(ws + XCAT_B + 3 * KV_B);
  float* M    = (float*)(ws + XCAT_B + 4 * KV_B);
  float* A    = (float*)(ws + XCAT_B + 4 * KV_B + (size_t)8 * 64 * 64 * 4);
  // total ws usage ~48.3 MiB

  hipMemsetAsync(M, 0, (size_t)8 * 64 * 64 * 4, stream);

  kv_proj<<<dim3(64, 8), 256, 0, stream>>>(x_skip, kv1_w, kv1_b, kv2_w, kv2_b,
                                           K1t, V1t, K2t, V2t);
  attn_spatial<<<dim3(64, 8), 256, 0, stream>>>(x_up, x_skip, K1t, V1t, xcat);
  chan_gram<<<dim3(16, 8), 256, 0, stream>>>(x_up, K2t, M);
  chan_softmax<<<8, 64, 0, stream>>>(M, A);
  chan_apply<<<dim3(64, 8), 256, 0, stream>>>(V2t, A, x_up, x_skip, xcat);
  conv_bn_relu<<<dim3(16, 8, 8), 256, 0, stream>>>(xcat, conv_w, bn_g, bn_b,
                                                   bn_m, bn_v, out);
}

// Round 2
// 540.772 us; speedup vs baseline: 2.4754x; 2.4754x over previous
//
#include <hip/hip_runtime.h>
#include <math.h>

#define HW 4096

typedef __attribute__((ext_vector_type(8))) short bh8;
typedef __attribute__((ext_vector_type(4))) float f32x4;
typedef unsigned int u32;
typedef unsigned short u16;

__device__ __forceinline__ u16 f2bf(float f) {
  union { float f; u32 u; } v; v.f = f;
  u32 u = v.u;
  return (u16)((u + 0x7FFFu + ((u >> 16) & 1u)) >> 16);
}

// ---------------------------------------------------------------------------
// kv projection. Branch 1 (spatial attn): K1 -> bf16 n-major (b,4096,64),
// V1 -> bf16 ch-major (b,64,4096). Branch 2 (channel attn): fp32 ch-major.
// grid (64 nblk, 8 b), block 256
// ---------------------------------------------------------------------------
__global__ __launch_bounds__(256) void kv_proj(
    const float* __restrict__ xs,
    const float* __restrict__ w1, const float* __restrict__ b1,
    const float* __restrict__ w2, const float* __restrict__ b2,
    u32* __restrict__ Knm, u16* __restrict__ Vcm,
    float* __restrict__ K2t, float* __restrict__ V2t) {
  __shared__ float Ss[64][65];
  __shared__ float Ws[128 * 64];
  __shared__ u32 LtK[64][33];  // packed bf16x2 K rows, conflict-free pitch
  const int b = blockIdx.y, n0 = blockIdx.x * 64;
  const int t = threadIdx.x;
  const int lane_n = t & 63, jg = t >> 6;
  const int jbase = jg * 32;
  const float* xsb = xs + (size_t)b * 128 * HW;

  for (int br = 0; br < 2; ++br) {
    const float* W = br ? w2 : w1;
    const float* bias = br ? b2 : b1;
    const float* src = xsb + (br ? 64 * HW : 0);
    __syncthreads();
    for (int s = 0; s < 16; ++s) {
      int ch = s * 4 + jg;
      Ss[ch][lane_n] = src[(size_t)ch * HW + n0 + lane_n];
    }
    for (int i = t; i < 128 * 64; i += 256) Ws[i] = W[i];
    __syncthreads();

    float acc[32];
#pragma unroll
    for (int i = 0; i < 32; ++i) acc[i] = bias[jbase + i];
    for (int ch = 0; ch < 64; ++ch) {
      float s = Ss[ch][lane_n];
#pragma unroll
      for (int i = 0; i < 32; ++i) acc[i] = fmaf(Ws[(jbase + i) * 64 + ch], s, acc[i]);
    }

    if (br == 0) {
      if (jg < 2) {  // K channels jbase..jbase+31 -> pack to LDS
#pragma unroll
        for (int i2 = 0; i2 < 16; ++i2) {
          u32 p = (u32)f2bf(acc[2 * i2]) | ((u32)f2bf(acc[2 * i2 + 1]) << 16);
          LtK[lane_n][jg * 16 + i2] = p;
        }
      } else {  // V channels (jbase-64)..+31 -> bf16 ch-major global
#pragma unroll
        for (int i = 0; i < 32; ++i) {
          int ch = jbase - 64 + i;
          Vcm[((size_t)b * 64 + ch) * HW + n0 + lane_n] = f2bf(acc[i]);
        }
      }
      __syncthreads();
      // coalesced n-major K write: rows of 32 uints (64 bf16)
#pragma unroll
      for (int p = 0; p < 8; ++p) {
        int idx = p * 256 + t;
        int n = idx >> 5, cc = idx & 31;
        Knm[((size_t)b * HW + n0 + n) * 32 + cc] = LtK[n][cc];
      }
    } else {
      float* Kt = K2t + (size_t)b * 64 * HW;
      float* Vt = V2t + (size_t)b * 64 * HW;
#pragma unroll
      for (int i = 0; i < 32; ++i) {
        int j = jbase + i;
        float* dst = (j < 64) ? (Kt + (size_t)j * HW) : (Vt + (size_t)(j - 64) * HW);
        dst[n0 + lane_n] = acc[i];
      }
    }
  }
}

// ---------------------------------------------------------------------------
// MFMA flash attention (spatial branch) + shortcut1, bf16 16x16x32.
// Block: 256 thr = 4 waves, 64 queries (16 q/wave). Bk=128 keys/iter.
// K LDS (k,ch) pitch 72 bf16; V LDS (ch,k) pitch 136; P per-wave (q,k) 136.
// grid (64 qblk, 8 b)
// ---------------------------------------------------------------------------
__global__ __launch_bounds__(256) void attn_mfma(
    const float* __restrict__ xu, const float* __restrict__ xs,
    const u16* __restrict__ Knm, const u16* __restrict__ Vcm,
    float* __restrict__ xcat) {
  __shared__ __align__(16) u16 Ks[128 * 72];
  __shared__ __align__(16) u16 Vs[64 * 136];
  __shared__ __align__(16) u16 Ps[4][16 * 136];
  const int b = blockIdx.y, q0 = blockIdx.x * 64;
  const int t = threadIdx.x;
  const int wq = t >> 6, lane = t & 63, lq = lane & 15, quad = lane >> 4;
  const float* xub = xu + (size_t)b * 128 * HW;
  const float* xsb = xs + (size_t)b * 128 * HW;
  const u16* Kb = Knm + (size_t)b * HW * 64;
  const u16* Vb = Vcm + (size_t)b * 64 * HW;

  // Q A-fragments in registers for the whole K loop (2 ch-steps of 32)
  bh8 qa[2];
  {
    int qrow = q0 + wq * 16 + lq;
#pragma unroll
    for (int s = 0; s < 2; ++s)
#pragma unroll
      for (int j = 0; j < 8; ++j) {
        int ch = s * 32 + quad * 8 + j;
        qa[s][j] = (short)f2bf(xub[(size_t)ch * HW + qrow]);
      }
  }

  f32x4 S[8], O[4];
#pragma unroll
  for (int i = 0; i < 4; ++i) O[i] = (f32x4)(0.f);
  float m[4], l[4];
#pragma unroll
  for (int r = 0; r < 4; ++r) { m[r] = -1e30f; l[r] = 0.f; }

  for (int kb = 0; kb < 32; ++kb) {
    const int n0 = kb * 128;
    __syncthreads();
    // stage K: 128 rows x 64 ch bf16, 16B chunks, coalesced
#pragma unroll
    for (int p = 0; p < 4; ++p) {
      int idx = p * 256 + t;
      int row = idx >> 3, c = idx & 7;
      uint4 d = *(const uint4*)(Kb + (size_t)(n0 + row) * 64 + c * 8);
      *(uint4*)&Ks[row * 72 + c * 8] = d;
    }
    // stage V: 64 ch-rows x 128 k bf16
#pragma unroll
    for (int p = 0; p < 4; ++p) {
      int idx = p * 256 + t;
      int ch = idx >> 4, c = idx & 15;
      uint4 d = *(const uint4*)(Vb + (size_t)ch * HW + n0 + c * 8);
      *(uint4*)&Vs[ch * 136 + c * 8] = d;
    }
    __syncthreads();

    // S = Q K^T : 8 key tiles of 16
#pragma unroll
    for (int kt = 0; kt < 8; ++kt) {
      const u16* krow = &Ks[(kt * 16 + lq) * 72 + quad * 8];
      bh8 b0 = *(const bh8*)(krow);
      bh8 b1 = *(const bh8*)(krow + 32);
      f32x4 acc = (f32x4)(0.f);
      acc = __builtin_amdgcn_mfma_f32_16x16x32_bf16(qa[0], b0, acc, 0, 0, 0);
      acc = __builtin_amdgcn_mfma_f32_16x16x32_bf16(qa[1], b1, acc, 0, 0, 0);
      S[kt] = acc;
    }

    // online softmax (row q = quad*4+r, cols spread over lanes 0..15 of quad)
    float alpha[4], rs[4];
#pragma unroll
    for (int r = 0; r < 4; ++r) {
      float mx = S[0][r];
#pragma unroll
      for (int kt = 1; kt < 8; ++kt) mx = fmaxf(mx, S[kt][r]);
      mx = fmaxf(mx, __shfl_xor(mx, 1));
      mx = fmaxf(mx, __shfl_xor(mx, 2));
      mx = fmaxf(mx, __shfl_xor(mx, 4));
      mx = fmaxf(mx, __shfl_xor(mx, 8));
      float mn = fmaxf(m[r], mx);
      alpha[r] = __expf(m[r] - mn);
      m[r] = mn;
      rs[r] = 0.f;
    }
#pragma unroll
    for (int kt = 0; kt < 8; ++kt)
#pragma unroll
      for (int r = 0; r < 4; ++r) {
        float p = __expf(S[kt][r] - m[r]);
        S[kt][r] = p;
        rs[r] += p;
      }
#pragma unroll
    for (int r = 0; r < 4; ++r) {
      float s = rs[r];
      s += __shfl_xor(s, 1);
      s += __shfl_xor(s, 2);
      s += __shfl_xor(s, 4);
      s += __shfl_xor(s, 8);
      l[r] = l[r] * alpha[r] + s;
    }
#pragma unroll
    for (int ct = 0; ct < 4; ++ct)
#pragma unroll
      for (int r = 0; r < 4; ++r) O[ct][r] *= alpha[r];

    // P: C-layout regs -> wave-private LDS (q,k) for A-layout reads
    u16* Pw = &Ps[wq][0];
#pragma unroll
    for (int kt = 0; kt < 8; ++kt)
#pragma unroll
      for (int r = 0; r < 4; ++r)
        Pw[(quad * 4 + r) * 136 + kt * 16 + lq] = f2bf(S[kt][r]);

    // O += P V : 4 k-steps of 32, 4 ch tiles of 16
#pragma unroll
    for (int ks = 0; ks < 4; ++ks) {
      bh8 pa = *(const bh8*)&Pw[lq * 136 + ks * 32 + quad * 8];
#pragma unroll
      for (int ct = 0; ct < 4; ++ct) {
        bh8 vb = *(const bh8*)&Vs[(ct * 16 + lq) * 136 + ks * 32 + quad * 8];
        O[ct] = __builtin_amdgcn_mfma_f32_16x16x32_bf16(pa, vb, O[ct], 0, 0, 0);
      }
    }
  }

  // epilogue: normalize, transpose via LDS, coalesced ch-major store + shortcut
  __syncthreads();
  float* Osc = (float*)&Ks[0];  // [64 ch][68 q] = 17408 B, fits in Ks
  float invl[4];
#pragma unroll
  for (int r = 0; r < 4; ++r) invl[r] = 1.f / l[r];
#pragma unroll
  for (int ct = 0; ct < 4; ++ct)
#pragma unroll
    for (int r = 0; r < 4; ++r)
      Osc[(ct * 16 + lq) * 68 + wq * 16 + quad * 4 + r] = O[ct][r] * invl[r];
  __syncthreads();
  float* ob = xcat + (size_t)b * 128 * HW;
#pragma unroll
  for (int p = 0; p < 16; ++p) {
    int idx = p * 256 + t;
    int ch = idx >> 6, q = idx & 63;
    size_t g = (size_t)ch * HW + q0 + q;
    ob[g] = Osc[ch * 68 + q] + xub[g] + xsb[g];
  }
}

// ---------------------------------------------------------------------------
// Channel gram partials: Mp[chunk][b][c][d] = sum over 128 n of u2[c,n]k2[d,n]
// grid (32 nchunk, 8 b), block 256. Fully LDS-tiled, coalesced, no atomics.
// ---------------------------------------------------------------------------
__global__ __launch_bounds__(256) void chan_gram(
    const float* __restrict__ xu, const float* __restrict__ K2t,
    float* __restrict__ Mp) {
  __shared__ float Us[64][65], Ksm[64][65];
  const int b = blockIdx.y, n0 = blockIdx.x * 128;
  const int t = threadIdx.x, c = t & 63, dg = t >> 6;
  const float* ub = xu + ((size_t)b * 128 + 64) * HW;
  const float* kb = K2t + (size_t)b * 64 * HW;
  float acc[16];
#pragma unroll
  for (int i = 0; i < 16; ++i) acc[i] = 0.f;
  for (int s = 0; s < 2; ++s) {
    int nn = n0 + s * 64;
    __syncthreads();
    for (int r = 0; r < 16; ++r) {
      int row = r * 4 + dg;
      Us[row][c] = ub[(size_t)row * HW + nn + c];
      Ksm[row][c] = kb[(size_t)row * HW + nn + c];
    }
    __syncthreads();
    for (int n = 0; n < 64; ++n) {
      float u = Us[c][n];
#pragma unroll
      for (int i = 0; i < 16; ++i) acc[i] = fmaf(Ksm[dg * 16 + i][n], u, acc[i]);
    }
  }
  float* dst = Mp + ((size_t)blockIdx.x * 8 + b) * 4096 + c * 64 + dg * 16;
#pragma unroll
  for (int i = 0; i < 16; ++i) dst[i] = acc[i];
}

// reduce 32 chunk-partials -> M. grid 128, block 256.
__global__ void chan_reduce(const float* __restrict__ Mp, float* __restrict__ M) {
  int idx = blockIdx.x * 256 + threadIdx.x;  // 32768 cells
  float s = 0.f;
  for (int ch = 0; ch < 32; ++ch) s += Mp[(size_t)ch * 32768 + idx];
  M[idx] = s;
}

// softmax over c (axis=1) for each (b, d). grid 8, block 64 (lane = d).
__global__ void chan_softmax(const float* __restrict__ M, float* __restrict__ A) {
  const int b = blockIdx.x, d = threadIdx.x;
  const float* Mb = M + b * 4096;
  float* Ab = A + b * 4096;
  float mx = -1e30f;
  for (int c = 0; c < 64; ++c) mx = fmaxf(mx, Mb[c * 64 + d]);
  float s = 0.f;
  for (int c = 0; c < 64; ++c) {
    float e = __expf(Mb[c * 64 + d] - mx);
    Ab[c * 64 + d] = e;
    s += e;
  }
  float inv = 1.f / s;
  for (int c = 0; c < 64; ++c) Ab[c * 64 + d] *= inv;
}

// ---------------------------------------------------------------------------
// cout[n][d] = sum_c v2[n][c] * A[c][d]; + shortcut2; write channels 64..127.
// grid (64 nblk, 8 b), block 256
// ---------------------------------------------------------------------------
__global__ __launch_bounds__(256) void chan_apply(
    const float* __restrict__ V2t, const float* __restrict__ A,
    const float* __restrict__ xu, const float* __restrict__ xs,
    float* __restrict__ xcat) {
  __shared__ float Vsm[64][65];
  __shared__ float As[64][65];
  const int b = blockIdx.y, n0 = blockIdx.x * 64, t = threadIdx.x;
  const int lane = t & 63, dg = t >> 6;
  const float* Vb = V2t + (size_t)b * 64 * HW;
  for (int s = 0; s < 16; ++s) {
    int c = s * 4 + dg;
    Vsm[lane][c] = Vb[(size_t)c * HW + n0 + lane];
  }
  for (int idx = t; idx < 4096; idx += 256) As[idx >> 6][idx & 63] = A[b * 4096 + idx];
  __syncthreads();

  float acc[16];
#pragma unroll
  for (int i = 0; i < 16; ++i) acc[i] = 0.f;
  for (int c = 0; c < 64; ++c) {
    float v = Vsm[lane][c];
#pragma unroll
    for (int i = 0; i < 16; ++i) acc[i] = fmaf(v, As[c][dg * 16 + i], acc[i]);
  }
  const float* xub = xu + ((size_t)b * 128 + 64) * HW;
  const float* xsb = xs + ((size_t)b * 128 + 64) * HW;
  float* ob = xcat + ((size_t)b * 128 + 64) * HW;
  const int n = n0 + lane;
#pragma unroll
  for (int i = 0; i < 16; ++i) {
    int d = dg * 16 + i;
    ob[(size_t)d * HW + n] = acc[i] + xub[(size_t)d * HW + n] + xsb[(size_t)d * HW + n];
  }
}

// ---------------------------------------------------------------------------
// Direct 3x3 SAME conv + BN + ReLU. grid (16 rowblk, 8 ocblk, 8 b), block 256.
// ---------------------------------------------------------------------------
__global__ __launch_bounds__(256) void conv_bn_relu(
    const float* __restrict__ x, const float* __restrict__ cw,
    const float* __restrict__ gamma, const float* __restrict__ beta,
    const float* __restrict__ mean, const float* __restrict__ var,
    float* __restrict__ out) {
  __shared__ float In[8][6][68];
  __shared__ float Wt[16 * 8 * 9];
  const int b = blockIdx.z, oc0 = blockIdx.y * 16, r0 = blockIdx.x * 4;
  const int t = threadIdx.x;
  const int ocl = t >> 4, oc = oc0 + ocl, wg = t & 15, w0 = wg * 4;
  const float* xb = x + (size_t)b * 128 * HW;

  float acc[4][4];
#pragma unroll
  for (int r = 0; r < 4; ++r)
#pragma unroll
    for (int j = 0; j < 4; ++j) acc[r][j] = 0.f;

  for (int icb = 0; icb < 128; icb += 8) {
    __syncthreads();
    for (int idx = t; idx < 8 * 6 * 68; idx += 256) {
      int ic = idx / 408;
      int rem = idx - ic * 408;
      int ir = rem / 68;
      int col = rem - ir * 68;
      int h = r0 - 1 + ir;
      int w = col - 1;
      float v = 0.f;
      if (col < 66 && (unsigned)h < 64u && (unsigned)w < 64u)
        v = xb[(size_t)(icb + ic) * HW + h * 64 + w];
      In[ic][ir][col] = v;
    }
    for (int idx = t; idx < 16 * 8 * 9; idx += 256) {
      int o = idx / 72;
      int rem = idx - o * 72;
      Wt[idx] = cw[((size_t)(oc0 + o) * 128 + icb) * 9 + rem];
    }
    __syncthreads();

    for (int ic = 0; ic < 8; ++ic) {
      float wreg[9];
#pragma unroll
      for (int i = 0; i < 9; ++i) wreg[i] = Wt[(ocl * 8 + ic) * 9 + i];
#pragma unroll
      for (int ir = 0; ir < 6; ++ir) {
        float4 a4 = *(const float4*)&In[ic][ir][w0];
        float2 b2 = *(const float2*)&In[ic][ir][w0 + 4];
        float iv[6] = {a4.x, a4.y, a4.z, a4.w, b2.x, b2.y};
        int rlo = ir - 2 < 0 ? 0 : ir - 2;
        int rhi = ir < 3 ? ir : 3;
#pragma unroll
        for (int r = 0; r < 4; ++r) {
          if (r < rlo || r > rhi) continue;
          int dh = ir - r;
#pragma unroll
          for (int dw = 0; dw < 3; ++dw) {
            float wv = wreg[dh * 3 + dw];
            acc[r][0] = fmaf(wv, iv[dw + 0], acc[r][0]);
            acc[r][1] = fmaf(wv, iv[dw + 1], acc[r][1]);
            acc[r][2] = fmaf(wv, iv[dw + 2], acc[r][2]);
            acc[r][3] = fmaf(wv, iv[dw + 3], acc[r][3]);
          }
        }
      }
    }
  }

  float inv = rsqrtf(var[oc] + 1e-5f);
  float sc = inv * gamma[oc];
  float sh = beta[oc] - mean[oc] * sc;
  float* ob = out + ((size_t)b * 128 + oc) * HW + r0 * 64 + w0;
#pragma unroll
  for (int r = 0; r < 4; ++r) {
    float4 v;
    v.x = fmaxf(fmaf(acc[r][0], sc, sh), 0.f);
    v.y = fmaxf(fmaf(acc[r][1], sc, sh), 0.f);
    v.z = fmaxf(fmaf(acc[r][2], sc, sh), 0.f);
    v.w = fmaxf(fmaf(acc[r][3], sc, sh), 0.f);
    *(float4*)&ob[r * 64] = v;
  }
}

// ---------------------------------------------------------------------------
extern "C" void kernel_launch(void* const* d_in, const int* in_sizes, int n_in,
                              void* d_out, int out_size, void* d_ws, size_t ws_size,
                              hipStream_t stream) {
  const float* x_up   = (const float*)d_in[0];
  const float* x_skip = (const float*)d_in[1];
  const float* kv1_w  = (const float*)d_in[2];
  const float* kv1_b  = (const float*)d_in[3];
  const float* kv2_w  = (const float*)d_in[4];
  const float* kv2_b  = (const float*)d_in[5];
  const float* conv_w = (const float*)d_in[6];
  const float* bn_g   = (const float*)d_in[7];
  const float* bn_b   = (const float*)d_in[8];
  const float* bn_m   = (const float*)d_in[9];
  const float* bn_v   = (const float*)d_in[10];
  float* out = (float*)d_out;

  char* ws = (char*)d_ws;
  const size_t XCAT_B = (size_t)8 * 128 * HW * 4;   // 16.78 MB
  const size_t KV32_B = (size_t)8 * 64 * HW * 4;    // 8.39 MB
  const size_t KV16_B = (size_t)8 * 64 * HW * 2;    // 4.19 MB
  size_t off = 0;
  float* xcat = (float*)(ws + off); off += XCAT_B;
  float* K2t  = (float*)(ws + off); off += KV32_B;
  float* V2t  = (float*)(ws + off); off += KV32_B;
  u32*   Knm  = (u32*)(ws + off);   off += KV16_B;
  u16*   Vcm  = (u16*)(ws + off);   off += KV16_B;
  float* Mp   = (float*)(ws + off); off += (size_t)32 * 8 * 4096 * 4;  // 4.19 MB
  float* M    = (float*)(ws + off); off += (size_t)8 * 4096 * 4;
  float* A    = (float*)(ws + off); off += (size_t)8 * 4096 * 4;
  // total ~46.5 MiB

  kv_proj<<<dim3(64, 8), 256, 0, stream>>>(x_skip, kv1_w, kv1_b, kv2_w, kv2_b,
                                           Knm, Vcm, K2t, V2t);
  attn_mfma<<<dim3(64, 8), 256, 0, stream>>>(x_up, x_skip, (const u16*)Knm, Vcm, xcat);
  chan_gram<<<dim3(32, 8), 256, 0, stream>>>(x_up, K2t, Mp);
  chan_reduce<<<128, 256, 0, stream>>>(Mp, M);
  chan_softmax<<<8, 64, 0, stream>>>(M, A);
  chan_apply<<<dim3(64, 8), 256, 0, stream>>>(V2t, A, x_up, x_skip, xcat);
  conv_bn_relu<<<dim3(16, 8, 8), 256, 0, stream>>>(xcat, conv_w, bn_g, bn_b,
                                                   bn_m, bn_v, out);
}

// Round 4
// 386.795 us; speedup vs baseline: 3.4608x; 1.3981x over previous
//
#include <hip/hip_runtime.h>
#include <math.h>

#define HW 4096

typedef __attribute__((ext_vector_type(8))) short bh8;
typedef __attribute__((ext_vector_type(4))) float f32x4;
typedef unsigned int u32;
typedef unsigned short u16;

__device__ __forceinline__ u16 f2bf(float f) {
  union { float f; u32 u; } v; v.f = f;
  u32 u = v.u;
  return (u16)((u + 0x7FFFu + ((u >> 16) & 1u)) >> 16);
}

// ---------------------------------------------------------------------------
// kv projection. Branch 1 (spatial attn): K1 -> bf16 n-major (b,4096,64),
// V1 -> bf16 ch-major (b,64,4096). Branch 2 (channel attn): fp32 ch-major.
// grid (64 nblk, 8 b), block 256
// ---------------------------------------------------------------------------
__global__ __launch_bounds__(256) void kv_proj(
    const float* __restrict__ xs,
    const float* __restrict__ w1, const float* __restrict__ b1,
    const float* __restrict__ w2, const float* __restrict__ b2,
    u32* __restrict__ Knm, u16* __restrict__ Vcm,
    float* __restrict__ K2t, float* __restrict__ V2t) {
  __shared__ float Ss[64][65];
  __shared__ float Ws[128 * 64];
  __shared__ u32 LtK[64][33];  // packed bf16x2 K rows, conflict-free pitch
  const int b = blockIdx.y, n0 = blockIdx.x * 64;
  const int t = threadIdx.x;
  const int lane_n = t & 63, jg = t >> 6;
  const int jbase = jg * 32;
  const float* xsb = xs + (size_t)b * 128 * HW;

  for (int br = 0; br < 2; ++br) {
    const float* W = br ? w2 : w1;
    const float* bias = br ? b2 : b1;
    const float* src = xsb + (br ? 64 * HW : 0);
    __syncthreads();
    for (int s = 0; s < 16; ++s) {
      int ch = s * 4 + jg;
      Ss[ch][lane_n] = src[(size_t)ch * HW + n0 + lane_n];
    }
    for (int i = t; i < 128 * 64; i += 256) Ws[i] = W[i];
    __syncthreads();

    float acc[32];
#pragma unroll
    for (int i = 0; i < 32; ++i) acc[i] = bias[jbase + i];
    for (int ch = 0; ch < 64; ++ch) {
      float s = Ss[ch][lane_n];
#pragma unroll
      for (int i = 0; i < 32; ++i) acc[i] = fmaf(Ws[(jbase + i) * 64 + ch], s, acc[i]);
    }

    if (br == 0) {
      if (jg < 2) {  // K channels jbase..jbase+31 -> pack to LDS
#pragma unroll
        for (int i2 = 0; i2 < 16; ++i2) {
          u32 p = (u32)f2bf(acc[2 * i2]) | ((u32)f2bf(acc[2 * i2 + 1]) << 16);
          LtK[lane_n][jg * 16 + i2] = p;
        }
      } else {  // V channels (jbase-64)..+31 -> bf16 ch-major global
#pragma unroll
        for (int i = 0; i < 32; ++i) {
          int ch = jbase - 64 + i;
          Vcm[((size_t)b * 64 + ch) * HW + n0 + lane_n] = f2bf(acc[i]);
        }
      }
      __syncthreads();
      // coalesced n-major K write: rows of 32 uints (64 bf16)
#pragma unroll
      for (int p = 0; p < 8; ++p) {
        int idx = p * 256 + t;
        int n = idx >> 5, cc = idx & 31;
        Knm[((size_t)b * HW + n0 + n) * 32 + cc] = LtK[n][cc];
      }
    } else {
      float* Kt = K2t + (size_t)b * 64 * HW;
      float* Vt = V2t + (size_t)b * 64 * HW;
#pragma unroll
      for (int i = 0; i < 32; ++i) {
        int j = jbase + i;
        float* dst = (j < 64) ? (Kt + (size_t)j * HW) : (Vt + (size_t)(j - 64) * HW);
        dst[n0 + lane_n] = acc[i];
      }
    }
  }
}

// ---------------------------------------------------------------------------
// MFMA flash attention (spatial branch) + shortcut1, bf16 16x16x32.
// Writes xcat_bf rows (b, n, ch 0..63) in bf16 n-major layout.
// grid (64 qblk, 8 b), block 256
// ---------------------------------------------------------------------------
__global__ __launch_bounds__(256) void attn_mfma(
    const float* __restrict__ xu, const float* __restrict__ xs,
    const u16* __restrict__ Knm, const u16* __restrict__ Vcm,
    u16* __restrict__ xcat) {
  __shared__ __align__(16) u16 Ks[128 * 72];
  __shared__ __align__(16) u16 Vs[64 * 136];
  __shared__ __align__(16) u16 Ps[4][16 * 136];
  const int b = blockIdx.y, q0 = blockIdx.x * 64;
  const int t = threadIdx.x;
  const int wq = t >> 6, lane = t & 63, lq = lane & 15, quad = lane >> 4;
  const float* xub = xu + (size_t)b * 128 * HW;
  const float* xsb = xs + (size_t)b * 128 * HW;
  const u16* Kb = Knm + (size_t)b * HW * 64;
  const u16* Vb = Vcm + (size_t)b * 64 * HW;

  // Q A-fragments in registers for the whole K loop (2 ch-steps of 32)
  bh8 qa[2];
  {
    int qrow = q0 + wq * 16 + lq;
#pragma unroll
    for (int s = 0; s < 2; ++s)
#pragma unroll
      for (int j = 0; j < 8; ++j) {
        int ch = s * 32 + quad * 8 + j;
        qa[s][j] = (short)f2bf(xub[(size_t)ch * HW + qrow]);
      }
  }

  f32x4 S[8], O[4];
#pragma unroll
  for (int i = 0; i < 4; ++i) O[i] = (f32x4)(0.f);
  float m[4], l[4];
#pragma unroll
  for (int r = 0; r < 4; ++r) { m[r] = -1e30f; l[r] = 0.f; }

  for (int kb = 0; kb < 32; ++kb) {
    const int n0 = kb * 128;
    __syncthreads();
    // stage K: 128 rows x 64 ch bf16, 16B chunks, coalesced
#pragma unroll
    for (int p = 0; p < 4; ++p) {
      int idx = p * 256 + t;
      int row = idx >> 3, c = idx & 7;
      uint4 d = *(const uint4*)(Kb + (size_t)(n0 + row) * 64 + c * 8);
      *(uint4*)&Ks[row * 72 + c * 8] = d;
    }
    // stage V: 64 ch-rows x 128 k bf16
#pragma unroll
    for (int p = 0; p < 4; ++p) {
      int idx = p * 256 + t;
      int ch = idx >> 4, c = idx & 15;
      uint4 d = *(const uint4*)(Vb + (size_t)ch * HW + n0 + c * 8);
      *(uint4*)&Vs[ch * 136 + c * 8] = d;
    }
    __syncthreads();

    // S = Q K^T : 8 key tiles of 16
#pragma unroll
    for (int kt = 0; kt < 8; ++kt) {
      const u16* krow = &Ks[(kt * 16 + lq) * 72 + quad * 8];
      bh8 b0 = *(const bh8*)(krow);
      bh8 b1 = *(const bh8*)(krow + 32);
      f32x4 acc = (f32x4)(0.f);
      acc = __builtin_amdgcn_mfma_f32_16x16x32_bf16(qa[0], b0, acc, 0, 0, 0);
      acc = __builtin_amdgcn_mfma_f32_16x16x32_bf16(qa[1], b1, acc, 0, 0, 0);
      S[kt] = acc;
    }

    // online softmax (row q = quad*4+r, cols spread over lanes 0..15 of quad)
    float alpha[4], rs[4];
#pragma unroll
    for (int r = 0; r < 4; ++r) {
      float mx = S[0][r];
#pragma unroll
      for (int kt = 1; kt < 8; ++kt) mx = fmaxf(mx, S[kt][r]);
      mx = fmaxf(mx, __shfl_xor(mx, 1));
      mx = fmaxf(mx, __shfl_xor(mx, 2));
      mx = fmaxf(mx, __shfl_xor(mx, 4));
      mx = fmaxf(mx, __shfl_xor(mx, 8));
      float mn = fmaxf(m[r], mx);
      alpha[r] = __expf(m[r] - mn);
      m[r] = mn;
      rs[r] = 0.f;
    }
#pragma unroll
    for (int kt = 0; kt < 8; ++kt)
#pragma unroll
      for (int r = 0; r < 4; ++r) {
        float p = __expf(S[kt][r] - m[r]);
        S[kt][r] = p;
        rs[r] += p;
      }
#pragma unroll
    for (int r = 0; r < 4; ++r) {
      float s = rs[r];
      s += __shfl_xor(s, 1);
      s += __shfl_xor(s, 2);
      s += __shfl_xor(s, 4);
      s += __shfl_xor(s, 8);
      l[r] = l[r] * alpha[r] + s;
    }
#pragma unroll
    for (int ct = 0; ct < 4; ++ct)
#pragma unroll
      for (int r = 0; r < 4; ++r) O[ct][r] *= alpha[r];

    // P: C-layout regs -> wave-private LDS (q,k) for A-layout reads
    u16* Pw = &Ps[wq][0];
#pragma unroll
    for (int kt = 0; kt < 8; ++kt)
#pragma unroll
      for (int r = 0; r < 4; ++r)
        Pw[(quad * 4 + r) * 136 + kt * 16 + lq] = f2bf(S[kt][r]);

    // O += P V : 4 k-steps of 32, 4 ch tiles of 16
#pragma unroll
    for (int ks = 0; ks < 4; ++ks) {
      bh8 pa = *(const bh8*)&Pw[lq * 136 + ks * 32 + quad * 8];
#pragma unroll
      for (int ct = 0; ct < 4; ++ct) {
        bh8 vb = *(const bh8*)&Vs[(ct * 16 + lq) * 136 + ks * 32 + quad * 8];
        O[ct] = __builtin_amdgcn_mfma_f32_16x16x32_bf16(pa, vb, O[ct], 0, 0, 0);
      }
    }
  }

  // epilogue: normalize, transpose via LDS, + shortcut1, bf16 n-major store
  __syncthreads();
  float* Osc = (float*)&Ks[0];  // [64 ch][68 q] = 17408 B, fits in Ks
  float invl[4];
#pragma unroll
  for (int r = 0; r < 4; ++r) invl[r] = 1.f / l[r];
#pragma unroll
  for (int ct = 0; ct < 4; ++ct)
#pragma unroll
    for (int r = 0; r < 4; ++r)
      Osc[(ct * 16 + lq) * 68 + wq * 16 + quad * 4 + r] = O[ct][r] * invl[r];
  __syncthreads();
  {
    const int q = lane;  // 0..63; chunk of 16 ch per wave
    u16 hv[16];
#pragma unroll
    for (int i = 0; i < 16; ++i) {
      int ch = wq * 16 + i;
      size_t g = (size_t)ch * HW + q0 + q;
      hv[i] = f2bf(Osc[ch * 68 + q] + xub[g] + xsb[g]);
    }
    u32 pk[8];
#pragma unroll
    for (int j = 0; j < 8; ++j) pk[j] = (u32)hv[2 * j] | ((u32)hv[2 * j + 1] << 16);
    u16* ob = xcat + ((size_t)b * HW + q0 + q) * 128 + wq * 16;
    *(uint4*)(ob) = make_uint4(pk[0], pk[1], pk[2], pk[3]);
    *(uint4*)(ob + 8) = make_uint4(pk[4], pk[5], pk[6], pk[7]);
  }
}

// ---------------------------------------------------------------------------
// Channel gram partials: Mp[chunk][b][c][d] = sum over 128 n of u2[c,n]k2[d,n]
// grid (32 nchunk, 8 b), block 256.
// ---------------------------------------------------------------------------
__global__ __launch_bounds__(256) void chan_gram(
    const float* __restrict__ xu, const float* __restrict__ K2t,
    float* __restrict__ Mp) {
  __shared__ float Us[64][65], Ksm[64][65];
  const int b = blockIdx.y, n0 = blockIdx.x * 128;
  const int t = threadIdx.x, c = t & 63, dg = t >> 6;
  const float* ub = xu + ((size_t)b * 128 + 64) * HW;
  const float* kb = K2t + (size_t)b * 64 * HW;
  float acc[16];
#pragma unroll
  for (int i = 0; i < 16; ++i) acc[i] = 0.f;
  for (int s = 0; s < 2; ++s) {
    int nn = n0 + s * 64;
    __syncthreads();
    for (int r = 0; r < 16; ++r) {
      int row = r * 4 + dg;
      Us[row][c] = ub[(size_t)row * HW + nn + c];
      Ksm[row][c] = kb[(size_t)row * HW + nn + c];
    }
    __syncthreads();
    for (int n = 0; n < 64; ++n) {
      float u = Us[c][n];
#pragma unroll
      for (int i = 0; i < 16; ++i) acc[i] = fmaf(Ksm[dg * 16 + i][n], u, acc[i]);
    }
  }
  float* dst = Mp + ((size_t)blockIdx.x * 8 + b) * 4096 + c * 64 + dg * 16;
#pragma unroll
  for (int i = 0; i < 16; ++i) dst[i] = acc[i];
}

// reduce 32 chunk-partials -> M. grid 128, block 256.
__global__ void chan_reduce(const float* __restrict__ Mp, float* __restrict__ M) {
  int idx = blockIdx.x * 256 + threadIdx.x;  // 32768 cells
  float s = 0.f;
  for (int ch = 0; ch < 32; ++ch) s += Mp[(size_t)ch * 32768 + idx];
  M[idx] = s;
}

// softmax over c (axis=1) for each (b, d). grid 8, block 64 (lane = d).
__global__ void chan_softmax(const float* __restrict__ M, float* __restrict__ A) {
  const int b = blockIdx.x, d = threadIdx.x;
  const float* Mb = M + b * 4096;
  float* Ab = A + b * 4096;
  float mx = -1e30f;
  for (int c = 0; c < 64; ++c) mx = fmaxf(mx, Mb[c * 64 + d]);
  float s = 0.f;
  for (int c = 0; c < 64; ++c) {
    float e = __expf(Mb[c * 64 + d] - mx);
    Ab[c * 64 + d] = e;
    s += e;
  }
  float inv = 1.f / s;
  for (int c = 0; c < 64; ++c) Ab[c * 64 + d] *= inv;
}

// ---------------------------------------------------------------------------
// cout[n][d] = sum_c v2[n][c] * A[c][d]; + shortcut2; write ch 64..127 of
// xcat_bf in bf16 n-major layout. grid (64 nblk, 8 b), block 256
// ---------------------------------------------------------------------------
__global__ __launch_bounds__(256) void chan_apply(
    const float* __restrict__ V2t, const float* __restrict__ A,
    const float* __restrict__ xu, const float* __restrict__ xs,
    u16* __restrict__ xcat) {
  __shared__ float Vsm[64][65];
  __shared__ float As[64][65];
  const int b = blockIdx.y, n0 = blockIdx.x * 64, t = threadIdx.x;
  const int lane = t & 63, dg = t >> 6;
  const float* Vb = V2t + (size_t)b * 64 * HW;
  for (int s = 0; s < 16; ++s) {
    int c = s * 4 + dg;
    Vsm[lane][c] = Vb[(size_t)c * HW + n0 + lane];
  }
  for (int idx = t; idx < 4096; idx += 256) As[idx >> 6][idx & 63] = A[b * 4096 + idx];
  __syncthreads();

  float acc[16];
#pragma unroll
  for (int i = 0; i < 16; ++i) acc[i] = 0.f;
  for (int c = 0; c < 64; ++c) {
    float v = Vsm[lane][c];
#pragma unroll
    for (int i = 0; i < 16; ++i) acc[i] = fmaf(v, As[c][dg * 16 + i], acc[i]);
  }
  const float* xub = xu + ((size_t)b * 128 + 64) * HW;
  const float* xsb = xs + ((size_t)b * 128 + 64) * HW;
  const int n = n0 + lane;
  u16 hv[16];
#pragma unroll
  for (int i = 0; i < 16; ++i) {
    int d = dg * 16 + i;
    hv[i] = f2bf(acc[i] + xub[(size_t)d * HW + n] + xsb[(size_t)d * HW + n]);
  }
  u32 pk[8];
#pragma unroll
  for (int j = 0; j < 8; ++j) pk[j] = (u32)hv[2 * j] | ((u32)hv[2 * j + 1] << 16);
  u16* ob = xcat + ((size_t)b * HW + n) * 128 + 64 + dg * 16;
  *(uint4*)(ob) = make_uint4(pk[0], pk[1], pk[2], pk[3]);
  *(uint4*)(ob + 8) = make_uint4(pk[4], pk[5], pk[6], pk[7]);
}

// ---------------------------------------------------------------------------
// Weight convert: conv_w (oc, ic, 3, 3) fp32 -> Wg[tap][oc][ic] bf16 with BN
// scale folded in; shb[oc] = BN shift. grid 576, block 256.
// ---------------------------------------------------------------------------
__global__ void wcvt(const float* __restrict__ w, const float* __restrict__ gamma,
                     const float* __restrict__ beta, const float* __restrict__ mean,
                     const float* __restrict__ var,
                     u16* __restrict__ Wg, float* __restrict__ shb) {
  int idx = blockIdx.x * 256 + threadIdx.x;
  if (idx < 147456) {
    int tap = idx >> 14;
    int oc = (idx >> 7) & 127;
    int ic = idx & 127;
    float sc = gamma[oc] * rsqrtf(var[oc] + 1e-5f);
    Wg[idx] = f2bf(w[((size_t)(oc * 128 + ic)) * 9 + tap] * sc);
  }
  if (idx < 128) {
    float sc = gamma[idx] * rsqrtf(var[idx] + 1e-5f);
    shb[idx] = beta[idx] - mean[idx] * sc;
  }
}

// ---------------------------------------------------------------------------
// Implicit-GEMM 3x3 conv via bf16 MFMA + fused BN(folded) + ReLU.
// Block: 256 thr = 4 waves. Tile: 128 spatial (2 h-rows x 64 w) x 128 oc.
// In LDS: 4 ih x 66 iw cells of 128 ic (272-B padded). Weights: per-tap slabs,
// double-buffered. K-loop: 9 taps x 4 ic-chunks of 32.
// grid (32 hblk, 8 b), block 256
// ---------------------------------------------------------------------------
__global__ __launch_bounds__(256) void conv_mfma(
    const u16* __restrict__ X, const u16* __restrict__ Wg,
    const float* __restrict__ shb, float* __restrict__ out) {
  __shared__ __align__(16) u16 In[4 * 66 * 136];
  __shared__ __align__(16) u16 Wt[2][128 * 136];
  const int b = blockIdx.y, h0 = blockIdx.x * 2;
  const int t = threadIdx.x;
  const int wq = t >> 6, lane = t & 63, lq = lane & 15, quad = lane >> 4;
  const u16* Xb = X + (size_t)b * HW * 128;

  // zero w-halo cells (iw = 0 and 65 for each ih)
  if (t < 128) {
    int ih = t >> 5, iwsel = (t >> 4) & 1, ck = t & 15;
    int iw = iwsel ? 65 : 0;
    *(uint4*)&In[(ih * 66 + iw) * 136 + ck * 8] = make_uint4(0, 0, 0, 0);
  }
  // stage input rows (zero h-halo out of range)
  for (int ih = 0; ih < 4; ++ih) {
    int h = h0 - 1 + ih;
    bool ok = (h >= 0 && h < 64);
    const u16* src = Xb + (size_t)h * 64 * 128;
#pragma unroll
    for (int p = 0; p < 4; ++p) {
      int idx = p * 256 + t;
      int row = idx >> 4, ck = idx & 15;
      uint4 d = make_uint4(0, 0, 0, 0);
      if (ok) d = *(const uint4*)(src + (size_t)row * 128 + ck * 8);
      *(uint4*)&In[(ih * 66 + 1 + row) * 136 + ck * 8] = d;
    }
  }
  // stage tap-0 weights into buffer 0 (128 oc x 16 chunks = 2048 uint4 = 8 passes)
  {
    const u16* src = Wg;
#pragma unroll
    for (int p = 0; p < 8; ++p) {
      int idx = p * 256 + t;
      int oc = idx >> 4, ck = idx & 15;
      uint4 d = *(const uint4*)(src + oc * 128 + ck * 8);
      *(uint4*)&Wt[0][oc * 136 + ck * 8] = d;
    }
  }
  __syncthreads();

  f32x4 acc[2][8];
#pragma unroll
  for (int mt = 0; mt < 2; ++mt)
#pragma unroll
    for (int nt = 0; nt < 8; ++nt) acc[mt][nt] = (f32x4)(0.f);

  for (int tap = 0; tap < 9; ++tap) {
    const int cur = tap & 1;
    if (tap < 8) {  // prefetch next tap into the other buffer (8 passes!)
      const u16* src = Wg + (size_t)(tap + 1) * 128 * 128;
#pragma unroll
      for (int p = 0; p < 8; ++p) {
        int idx = p * 256 + t;
        int oc = idx >> 4, ck = idx & 15;
        uint4 d = *(const uint4*)(src + oc * 128 + ck * 8);
        *(uint4*)&Wt[cur ^ 1][oc * 136 + ck * 8] = d;
      }
    }
    const int dh = tap / 3, dw = tap - 3 * dh;
    const u16* Wc = &Wt[cur][0];
#pragma unroll
    for (int c = 0; c < 4; ++c) {
      bh8 bf[8];
#pragma unroll
      for (int nt = 0; nt < 8; ++nt)
        bf[nt] = *(const bh8*)&Wc[(nt * 16 + lq) * 136 + c * 32 + quad * 8];
#pragma unroll
      for (int mt = 0; mt < 2; ++mt) {
        int s = (wq * 2 + mt) * 16 + lq;
        int ih = (s >> 6) + dh, iw = (s & 63) + dw;
        bh8 af = *(const bh8*)&In[(ih * 66 + iw) * 136 + c * 32 + quad * 8];
#pragma unroll
        for (int nt = 0; nt < 8; ++nt)
          acc[mt][nt] = __builtin_amdgcn_mfma_f32_16x16x32_bf16(af, bf[nt], acc[mt][nt], 0, 0, 0);
      }
    }
    __syncthreads();
  }

  // epilogue: +bias, ReLU, dense float4 stores (r -> consecutive w)
  float shv[8];
#pragma unroll
  for (int nt = 0; nt < 8; ++nt) shv[nt] = shb[nt * 16 + lq];
#pragma unroll
  for (int mt = 0; mt < 2; ++mt) {
    int mtile = wq * 2 + mt;
    int h = h0 + (mtile >> 2);
    int w0 = ((mtile & 3) * 16) + quad * 4;
#pragma unroll
    for (int nt = 0; nt < 8; ++nt) {
      int oc = nt * 16 + lq;
      float4 v;
      v.x = fmaxf(acc[mt][nt][0] + shv[nt], 0.f);
      v.y = fmaxf(acc[mt][nt][1] + shv[nt], 0.f);
      v.z = fmaxf(acc[mt][nt][2] + shv[nt], 0.f);
      v.w = fmaxf(acc[mt][nt][3] + shv[nt], 0.f);
      *(float4*)&out[((size_t)b * 128 + oc) * HW + h * 64 + w0] = v;
    }
  }
}

// ---------------------------------------------------------------------------
extern "C" void kernel_launch(void* const* d_in, const int* in_sizes, int n_in,
                              void* d_out, int out_size, void* d_ws, size_t ws_size,
                              hipStream_t stream) {
  const float* x_up   = (const float*)d_in[0];
  const float* x_skip = (const float*)d_in[1];
  const float* kv1_w  = (const float*)d_in[2];
  const float* kv1_b  = (const float*)d_in[3];
  const float* kv2_w  = (const float*)d_in[4];
  const float* kv2_b  = (const float*)d_in[5];
  const float* conv_w = (const float*)d_in[6];
  const float* bn_g   = (const float*)d_in[7];
  const float* bn_b   = (const float*)d_in[8];
  const float* bn_m   = (const float*)d_in[9];
  const float* bn_v   = (const float*)d_in[10];
  float* out = (float*)d_out;

  char* ws = (char*)d_ws;
  const size_t XCATB_B = (size_t)8 * HW * 128 * 2;  // 8.39 MB bf16 n-major
  const size_t KV32_B  = (size_t)8 * 64 * HW * 4;   // 8.39 MB
  const size_t KV16_B  = (size_t)8 * 64 * HW * 2;   // 4.19 MB
  size_t off = 0;
  u16*   xcat = (u16*)(ws + off);   off += XCATB_B;
  float* K2t  = (float*)(ws + off); off += KV32_B;
  float* V2t  = (float*)(ws + off); off += KV32_B;
  u32*   Knm  = (u32*)(ws + off);   off += KV16_B;
  u16*   Vcm  = (u16*)(ws + off);   off += KV16_B;
  float* Mp   = (float*)(ws + off); off += (size_t)32 * 8 * 4096 * 4;
  float* M    = (float*)(ws + off); off += (size_t)8 * 4096 * 4;
  float* A    = (float*)(ws + off); off += (size_t)8 * 4096 * 4;
  u16*   Wg   = (u16*)(ws + off);   off += (size_t)9 * 128 * 128 * 2;
  float* shb  = (float*)(ws + off); off += 128 * 4;

  wcvt<<<576, 256, 0, stream>>>(conv_w, bn_g, bn_b, bn_m, bn_v, Wg, shb);
  kv_proj<<<dim3(64, 8), 256, 0, stream>>>(x_skip, kv1_w, kv1_b, kv2_w, kv2_b,
                                           Knm, Vcm, K2t, V2t);
  attn_mfma<<<dim3(64, 8), 256, 0, stream>>>(x_up, x_skip, (const u16*)Knm, Vcm, xcat);
  chan_gram<<<dim3(32, 8), 256, 0, stream>>>(x_up, K2t, Mp);
  chan_reduce<<<128, 256, 0, stream>>>(Mp, M);
  chan_softmax<<<8, 64, 0, stream>>>(M, A);
  chan_apply<<<dim3(64, 8), 256, 0, stream>>>(V2t, A, x_up, x_skip, xcat);
  conv_mfma<<<dim3(32, 8), 256, 0, stream>>>(xcat, Wg, shb, out);
}

// Round 5
// 352.063 us; speedup vs baseline: 3.8022x; 1.0987x over previous
//
#include <hip/hip_runtime.h>
#include <math.h>

#define HW 4096

typedef __attribute__((ext_vector_type(8))) short bh8;
typedef __attribute__((ext_vector_type(4))) float f32x4;
typedef unsigned int u32;
typedef unsigned short u16;

__device__ __forceinline__ u16 f2bf(float f) {
  union { float f; u32 u; } v; v.f = f;
  u32 u = v.u;
  return (u16)((u + 0x7FFFu + ((u >> 16) & 1u)) >> 16);
}

// ---------------------------------------------------------------------------
// kv projection. Branch 1 (spatial attn): K1 -> bf16 n-major (b,4096,64),
// V1 -> bf16 ch-major (b,64,4096). Branch 2 (channel attn): fp32 ch-major.
// grid (64 nblk, 8 b), block 256
// ---------------------------------------------------------------------------
__global__ __launch_bounds__(256) void kv_proj(
    const float* __restrict__ xs,
    const float* __restrict__ w1, const float* __restrict__ b1,
    const float* __restrict__ w2, const float* __restrict__ b2,
    u32* __restrict__ Knm, u16* __restrict__ Vcm,
    float* __restrict__ K2t, float* __restrict__ V2t) {
  __shared__ float Ss[64][65];
  __shared__ float Ws[128 * 64];
  __shared__ u32 LtK[64][33];  // packed bf16x2 K rows, conflict-free pitch
  const int b = blockIdx.y, n0 = blockIdx.x * 64;
  const int t = threadIdx.x;
  const int lane_n = t & 63, jg = t >> 6;
  const int jbase = jg * 32;
  const float* xsb = xs + (size_t)b * 128 * HW;

  for (int br = 0; br < 2; ++br) {
    const float* W = br ? w2 : w1;
    const float* bias = br ? b2 : b1;
    const float* src = xsb + (br ? 64 * HW : 0);
    __syncthreads();
    for (int s = 0; s < 16; ++s) {
      int ch = s * 4 + jg;
      Ss[ch][lane_n] = src[(size_t)ch * HW + n0 + lane_n];
    }
    for (int i = t; i < 128 * 64; i += 256) Ws[i] = W[i];
    __syncthreads();

    float acc[32];
#pragma unroll
    for (int i = 0; i < 32; ++i) acc[i] = bias[jbase + i];
    for (int ch = 0; ch < 64; ++ch) {
      float s = Ss[ch][lane_n];
#pragma unroll
      for (int i = 0; i < 32; ++i) acc[i] = fmaf(Ws[(jbase + i) * 64 + ch], s, acc[i]);
    }

    if (br == 0) {
      if (jg < 2) {  // K channels jbase..jbase+31 -> pack to LDS
#pragma unroll
        for (int i2 = 0; i2 < 16; ++i2) {
          u32 p = (u32)f2bf(acc[2 * i2]) | ((u32)f2bf(acc[2 * i2 + 1]) << 16);
          LtK[lane_n][jg * 16 + i2] = p;
        }
      } else {  // V channels (jbase-64)..+31 -> bf16 ch-major global
#pragma unroll
        for (int i = 0; i < 32; ++i) {
          int ch = jbase - 64 + i;
          Vcm[((size_t)b * 64 + ch) * HW + n0 + lane_n] = f2bf(acc[i]);
        }
      }
      __syncthreads();
      // coalesced n-major K write: rows of 32 uints (64 bf16)
#pragma unroll
      for (int p = 0; p < 8; ++p) {
        int idx = p * 256 + t;
        int n = idx >> 5, cc = idx & 31;
        Knm[((size_t)b * HW + n0 + n) * 32 + cc] = LtK[n][cc];
      }
    } else {
      float* Kt = K2t + (size_t)b * 64 * HW;
      float* Vt = V2t + (size_t)b * 64 * HW;
#pragma unroll
      for (int i = 0; i < 32; ++i) {
        int j = jbase + i;
        float* dst = (j < 64) ? (Kt + (size_t)j * HW) : (Vt + (size_t)(j - 64) * HW);
        dst[n0 + lane_n] = acc[i];
      }
    }
  }
}

// ---------------------------------------------------------------------------
// MFMA flash attention (spatial branch) + shortcut1, bf16 16x16x32.
// Key-sliced waves: each of 4 waves owns a 32-key slice of each 128-key tile;
// computes S^T = K·Q^T (A=K, B=Q all 64 q), exp without max tracking
// (exp(S-12), uniform shift cancels in O/l), P packed b64 to wave-private
// LDS in (q,k) layout, PV swapped (O^T = V·P^T). Per-wave partial O over its
// key subset; cross-wave LDS reduce + normalize + shortcut at the end.
// grid (64 qblk, 8 b), block 256
// ---------------------------------------------------------------------------
__global__ __launch_bounds__(256) void attn_mfma(
    const float* __restrict__ xu, const float* __restrict__ xs,
    const u16* __restrict__ Knm, const u16* __restrict__ Vcm,
    u16* __restrict__ xcat) {
  __shared__ __align__(16) u16 SMEM[27136];  // 54272 B
  u16* Ks = SMEM;             // [128][72]  key-major
  u16* Vs = SMEM + 9216;      // [64][136]  ch-major
  u16* Pa = SMEM + 17920;     // [4 waves][64 q][36 k-pitch]
  const int b = blockIdx.y, q0 = blockIdx.x * 64;
  const int t = threadIdx.x;
  const int wq = t >> 6, lane = t & 63, lq = lane & 15, quad = lane >> 4;
  const int wb = wq * 32;  // wave's key-slice base
  const float* xub = xu + (size_t)b * 128 * HW;
  const float* xsb = xs + (size_t)b * 128 * HW;
  const u16* Kb = Knm + (size_t)b * HW * 64;
  const u16* Vb = Vcm + (size_t)b * 64 * HW;
  u16* Pw = Pa + wq * 64 * 36;

  // Q B-fragments: all 64 q x 64 ch per wave (B[n=q][k=ch])
  bh8 qb[4][2];
#pragma unroll
  for (int nt = 0; nt < 4; ++nt)
#pragma unroll
    for (int s = 0; s < 2; ++s)
#pragma unroll
      for (int j = 0; j < 8; ++j) {
        int ch = s * 32 + quad * 8 + j;
        qb[nt][s][j] = (short)f2bf(xub[(size_t)ch * HW + q0 + nt * 16 + lq]);
      }

  f32x4 O[4][4];  // [ct: ch-tile][nt: q-tile], C: row=ch_local, col=q_local
#pragma unroll
  for (int ct = 0; ct < 4; ++ct)
#pragma unroll
    for (int nt = 0; nt < 4; ++nt) O[ct][nt] = (f32x4)(0.f);
  float lsum[4] = {0.f, 0.f, 0.f, 0.f};

  for (int kb = 0; kb < 32; ++kb) {
    const int n0 = kb * 128;
    __syncthreads();
    // stage K: 128 rows x 64 ch bf16, coalesced
#pragma unroll
    for (int p = 0; p < 4; ++p) {
      int idx = p * 256 + t;
      int row = idx >> 3, c = idx & 7;
      uint4 d = *(const uint4*)(Kb + (size_t)(n0 + row) * 64 + c * 8);
      *(uint4*)&Ks[row * 72 + c * 8] = d;
    }
    // stage V: 64 ch-rows x 128 k bf16
#pragma unroll
    for (int p = 0; p < 4; ++p) {
      int idx = p * 256 + t;
      int ch = idx >> 4, c = idx & 15;
      uint4 d = *(const uint4*)(Vb + (size_t)ch * HW + n0 + c * 8);
      *(uint4*)&Vs[ch * 136 + c * 8] = d;
    }
    __syncthreads();

    // S^T = K Q^T on this wave's 32-key slice: D[key][q]
    f32x4 S[2][4];
#pragma unroll
    for (int mt = 0; mt < 2; ++mt) {
      const u16* krow = &Ks[(wb + mt * 16 + lq) * 72 + quad * 8];
      bh8 ka0 = *(const bh8*)(krow);
      bh8 ka1 = *(const bh8*)(krow + 32);
#pragma unroll
      for (int nt = 0; nt < 4; ++nt) {
        f32x4 acc = (f32x4)(0.f);
        acc = __builtin_amdgcn_mfma_f32_16x16x32_bf16(ka0, qb[nt][0], acc, 0, 0, 0);
        acc = __builtin_amdgcn_mfma_f32_16x16x32_bf16(ka1, qb[nt][1], acc, 0, 0, 0);
        S[mt][nt] = acc;
      }
    }

    // exp (no max tracking), accumulate per-lane l, pack P -> LDS (q,k) b64
#pragma unroll
    for (int mt = 0; mt < 2; ++mt)
#pragma unroll
      for (int nt = 0; nt < 4; ++nt) {
        float p0 = __expf(S[mt][nt][0] - 12.f);
        float p1 = __expf(S[mt][nt][1] - 12.f);
        float p2 = __expf(S[mt][nt][2] - 12.f);
        float p3 = __expf(S[mt][nt][3] - 12.f);
        lsum[nt] += (p0 + p1) + (p2 + p3);
        u32 lo = (u32)f2bf(p0) | ((u32)f2bf(p1) << 16);
        u32 hi = (u32)f2bf(p2) | ((u32)f2bf(p3) << 16);
        *(uint2*)&Pw[(nt * 16 + lq) * 36 + mt * 16 + quad * 4] = make_uint2(lo, hi);
      }

    // O^T += V · P^T : A=V[m=ch][k], B=P[n=q][k], 16 MFMA
    bh8 va[4];
#pragma unroll
    for (int ct = 0; ct < 4; ++ct)
      va[ct] = *(const bh8*)&Vs[(ct * 16 + lq) * 136 + wb + quad * 8];
#pragma unroll
    for (int nt = 0; nt < 4; ++nt) {
      bh8 pb = *(const bh8*)&Pw[(nt * 16 + lq) * 36 + quad * 8];
#pragma unroll
      for (int ct = 0; ct < 4; ++ct)
        O[ct][nt] = __builtin_amdgcn_mfma_f32_16x16x32_bf16(va[ct], pb, O[ct][nt], 0, 0, 0);
    }
  }

  // ---- epilogue: cross-wave reduce, normalize, shortcut, bf16 store ----
  // reduce lsum across quads (keys split over quads/regs within the wave)
#pragma unroll
  for (int nt = 0; nt < 4; ++nt) {
    lsum[nt] += __shfl_xor(lsum[nt], 16);
    lsum[nt] += __shfl_xor(lsum[nt], 32);
  }
  __syncthreads();  // all waves done reading Ks/Vs/Pa
  float* Posc = (float*)SMEM;           // [4 waves][32 ch][68 q] = 34816 B
  float* Lred = (float*)(SMEM + 17920); // [4 waves][4 nt][16 lq]
  if (quad == 0) {
#pragma unroll
    for (int nt = 0; nt < 4; ++nt) Lred[(wq * 4 + nt) * 16 + lq] = lsum[nt];
  }

  const int q = t & 63, cg = t >> 6;
#pragma unroll
  for (int rh = 0; rh < 2; ++rh) {
    if (rh) __syncthreads();  // previous half's readers done
    // write this wave's fp32 partials for ch half rh
#pragma unroll
    for (int c2 = 0; c2 < 2; ++c2)
#pragma unroll
      for (int nt = 0; nt < 4; ++nt)
#pragma unroll
        for (int r = 0; r < 4; ++r)
          Posc[(wq * 32 + c2 * 16 + quad * 4 + r) * 68 + nt * 16 + lq] =
              O[rh * 2 + c2][nt][r];
    __syncthreads();
    // emit: thread -> (q, 8 channels)
    float li = 0.f;
#pragma unroll
    for (int w2 = 0; w2 < 4; ++w2) li += Lred[w2 * 64 + q];
    float inv = 1.f / li;
    u16 h[8];
#pragma unroll
    for (int i = 0; i < 8; ++i) {
      int chl = cg * 8 + i;
      float s = 0.f;
#pragma unroll
      for (int w2 = 0; w2 < 4; ++w2) s += Posc[(w2 * 32 + chl) * 68 + q];
      int ch = rh * 32 + chl;
      size_t g = (size_t)ch * HW + q0 + q;
      h[i] = f2bf(s * inv + xub[g] + xsb[g]);
    }
    u32 pk[4];
#pragma unroll
    for (int j = 0; j < 4; ++j) pk[j] = (u32)h[2 * j] | ((u32)h[2 * j + 1] << 16);
    u16* ob = xcat + ((size_t)b * HW + q0 + q) * 128 + rh * 32 + cg * 8;
    *(uint4*)ob = make_uint4(pk[0], pk[1], pk[2], pk[3]);
  }
}

// ---------------------------------------------------------------------------
// Channel gram partials: Mp[chunk][b][c][d] = sum over 128 n of u2[c,n]k2[d,n]
// grid (32 nchunk, 8 b), block 256.
// ---------------------------------------------------------------------------
__global__ __launch_bounds__(256) void chan_gram(
    const float* __restrict__ xu, const float* __restrict__ K2t,
    float* __restrict__ Mp) {
  __shared__ float Us[64][65], Ksm[64][65];
  const int b = blockIdx.y, n0 = blockIdx.x * 128;
  const int t = threadIdx.x, c = t & 63, dg = t >> 6;
  const float* ub = xu + ((size_t)b * 128 + 64) * HW;
  const float* kb = K2t + (size_t)b * 64 * HW;
  float acc[16];
#pragma unroll
  for (int i = 0; i < 16; ++i) acc[i] = 0.f;
  for (int s = 0; s < 2; ++s) {
    int nn = n0 + s * 64;
    __syncthreads();
    for (int r = 0; r < 16; ++r) {
      int row = r * 4 + dg;
      Us[row][c] = ub[(size_t)row * HW + nn + c];
      Ksm[row][c] = kb[(size_t)row * HW + nn + c];
    }
    __syncthreads();
    for (int n = 0; n < 64; ++n) {
      float u = Us[c][n];
#pragma unroll
      for (int i = 0; i < 16; ++i) acc[i] = fmaf(Ksm[dg * 16 + i][n], u, acc[i]);
    }
  }
  float* dst = Mp + ((size_t)blockIdx.x * 8 + b) * 4096 + c * 64 + dg * 16;
#pragma unroll
  for (int i = 0; i < 16; ++i) dst[i] = acc[i];
}

// reduce 32 chunk-partials -> M. grid 128, block 256.
__global__ void chan_reduce(const float* __restrict__ Mp, float* __restrict__ M) {
  int idx = blockIdx.x * 256 + threadIdx.x;  // 32768 cells
  float s = 0.f;
  for (int ch = 0; ch < 32; ++ch) s += Mp[(size_t)ch * 32768 + idx];
  M[idx] = s;
}

// softmax over c (axis=1) for each (b, d). grid 8, block 64 (lane = d).
__global__ void chan_softmax(const float* __restrict__ M, float* __restrict__ A) {
  const int b = blockIdx.x, d = threadIdx.x;
  const float* Mb = M + b * 4096;
  float* Ab = A + b * 4096;
  float mx = -1e30f;
  for (int c = 0; c < 64; ++c) mx = fmaxf(mx, Mb[c * 64 + d]);
  float s = 0.f;
  for (int c = 0; c < 64; ++c) {
    float e = __expf(Mb[c * 64 + d] - mx);
    Ab[c * 64 + d] = e;
    s += e;
  }
  float inv = 1.f / s;
  for (int c = 0; c < 64; ++c) Ab[c * 64 + d] *= inv;
}

// ---------------------------------------------------------------------------
// cout[n][d] = sum_c v2[n][c] * A[c][d]; + shortcut2; write ch 64..127 of
// xcat_bf in bf16 n-major layout. grid (64 nblk, 8 b), block 256
// ---------------------------------------------------------------------------
__global__ __launch_bounds__(256) void chan_apply(
    const float* __restrict__ V2t, const float* __restrict__ A,
    const float* __restrict__ xu, const float* __restrict__ xs,
    u16* __restrict__ xcat) {
  __shared__ float Vsm[64][65];
  __shared__ float As[64][65];
  const int b = blockIdx.y, n0 = blockIdx.x * 64, t = threadIdx.x;
  const int lane = t & 63, dg = t >> 6;
  const float* Vb = V2t + (size_t)b * 64 * HW;
  for (int s = 0; s < 16; ++s) {
    int c = s * 4 + dg;
    Vsm[lane][c] = Vb[(size_t)c * HW + n0 + lane];
  }
  for (int idx = t; idx < 4096; idx += 256) As[idx >> 6][idx & 63] = A[b * 4096 + idx];
  __syncthreads();

  float acc[16];
#pragma unroll
  for (int i = 0; i < 16; ++i) acc[i] = 0.f;
  for (int c = 0; c < 64; ++c) {
    float v = Vsm[lane][c];
#pragma unroll
    for (int i = 0; i < 16; ++i) acc[i] = fmaf(v, As[c][dg * 16 + i], acc[i]);
  }
  const float* xub = xu + ((size_t)b * 128 + 64) * HW;
  const float* xsb = xs + ((size_t)b * 128 + 64) * HW;
  const int n = n0 + lane;
  u16 hv[16];
#pragma unroll
  for (int i = 0; i < 16; ++i) {
    int d = dg * 16 + i;
    hv[i] = f2bf(acc[i] + xub[(size_t)d * HW + n] + xsb[(size_t)d * HW + n]);
  }
  u32 pk[8];
#pragma unroll
  for (int j = 0; j < 8; ++j) pk[j] = (u32)hv[2 * j] | ((u32)hv[2 * j + 1] << 16);
  u16* ob = xcat + ((size_t)b * HW + n) * 128 + 64 + dg * 16;
  *(uint4*)(ob) = make_uint4(pk[0], pk[1], pk[2], pk[3]);
  *(uint4*)(ob + 8) = make_uint4(pk[4], pk[5], pk[6], pk[7]);
}

// ---------------------------------------------------------------------------
// Weight convert: conv_w (oc, ic, 3, 3) fp32 -> Wg[tap][oc][ic] bf16 with BN
// scale folded in; shb[oc] = BN shift. grid 576, block 256.
// ---------------------------------------------------------------------------
__global__ void wcvt(const float* __restrict__ w, const float* __restrict__ gamma,
                     const float* __restrict__ beta, const float* __restrict__ mean,
                     const float* __restrict__ var,
                     u16* __restrict__ Wg, float* __restrict__ shb) {
  int idx = blockIdx.x * 256 + threadIdx.x;
  if (idx < 147456) {
    int tap = idx >> 14;
    int oc = (idx >> 7) & 127;
    int ic = idx & 127;
    float sc = gamma[oc] * rsqrtf(var[oc] + 1e-5f);
    Wg[idx] = f2bf(w[((size_t)(oc * 128 + ic)) * 9 + tap] * sc);
  }
  if (idx < 128) {
    float sc = gamma[idx] * rsqrtf(var[idx] + 1e-5f);
    shb[idx] = beta[idx] - mean[idx] * sc;
  }
}

// ---------------------------------------------------------------------------
// Implicit-GEMM 3x3 conv via bf16 MFMA + fused BN(folded) + ReLU.
// Block: 256 thr = 4 waves. Tile: 128 spatial (2 h-rows x 64 w) x 128 oc.
// grid (32 hblk, 8 b), block 256
// ---------------------------------------------------------------------------
__global__ __launch_bounds__(256) void conv_mfma(
    const u16* __restrict__ X, const u16* __restrict__ Wg,
    const float* __restrict__ shb, float* __restrict__ out) {
  __shared__ __align__(16) u16 In[4 * 66 * 136];
  __shared__ __align__(16) u16 Wt[2][128 * 136];
  const int b = blockIdx.y, h0 = blockIdx.x * 2;
  const int t = threadIdx.x;
  const int wq = t >> 6, lane = t & 63, lq = lane & 15, quad = lane >> 4;
  const u16* Xb = X + (size_t)b * HW * 128;

  // zero w-halo cells (iw = 0 and 65 for each ih)
  if (t < 128) {
    int ih = t >> 5, iwsel = (t >> 4) & 1, ck = t & 15;
    int iw = iwsel ? 65 : 0;
    *(uint4*)&In[(ih * 66 + iw) * 136 + ck * 8] = make_uint4(0, 0, 0, 0);
  }
  // stage input rows (zero h-halo out of range)
  for (int ih = 0; ih < 4; ++ih) {
    int h = h0 - 1 + ih;
    bool ok = (h >= 0 && h < 64);
    const u16* src = Xb + (size_t)h * 64 * 128;
#pragma unroll
    for (int p = 0; p < 4; ++p) {
      int idx = p * 256 + t;
      int row = idx >> 4, ck = idx & 15;
      uint4 d = make_uint4(0, 0, 0, 0);
      if (ok) d = *(const uint4*)(src + (size_t)row * 128 + ck * 8);
      *(uint4*)&In[(ih * 66 + 1 + row) * 136 + ck * 8] = d;
    }
  }
  // stage tap-0 weights into buffer 0 (128 oc x 16 chunks = 2048 uint4 = 8 passes)
  {
    const u16* src = Wg;
#pragma unroll
    for (int p = 0; p < 8; ++p) {
      int idx = p * 256 + t;
      int oc = idx >> 4, ck = idx & 15;
      uint4 d = *(const uint4*)(src + oc * 128 + ck * 8);
      *(uint4*)&Wt[0][oc * 136 + ck * 8] = d;
    }
  }
  __syncthreads();

  f32x4 acc[2][8];
#pragma unroll
  for (int mt = 0; mt < 2; ++mt)
#pragma unroll
    for (int nt = 0; nt < 8; ++nt) acc[mt][nt] = (f32x4)(0.f);

  for (int tap = 0; tap < 9; ++tap) {
    const int cur = tap & 1;
    if (tap < 8) {  // prefetch next tap into the other buffer
      const u16* src = Wg + (size_t)(tap + 1) * 128 * 128;
#pragma unroll
      for (int p = 0; p < 8; ++p) {
        int idx = p * 256 + t;
        int oc = idx >> 4, ck = idx & 15;
        uint4 d = *(const uint4*)(src + oc * 128 + ck * 8);
        *(uint4*)&Wt[cur ^ 1][oc * 136 + ck * 8] = d;
      }
    }
    const int dh = tap / 3, dw = tap - 3 * dh;
    const u16* Wc = &Wt[cur][0];
#pragma unroll
    for (int c = 0; c < 4; ++c) {
      bh8 bf[8];
#pragma unroll
      for (int nt = 0; nt < 8; ++nt)
        bf[nt] = *(const bh8*)&Wc[(nt * 16 + lq) * 136 + c * 32 + quad * 8];
#pragma unroll
      for (int mt = 0; mt < 2; ++mt) {
        int s = (wq * 2 + mt) * 16 + lq;
        int ih = (s >> 6) + dh, iw = (s & 63) + dw;
        bh8 af = *(const bh8*)&In[(ih * 66 + iw) * 136 + c * 32 + quad * 8];
#pragma unroll
        for (int nt = 0; nt < 8; ++nt)
          acc[mt][nt] = __builtin_amdgcn_mfma_f32_16x16x32_bf16(af, bf[nt], acc[mt][nt], 0, 0, 0);
      }
    }
    __syncthreads();
  }

  // epilogue: +bias, ReLU, dense float4 stores
  float shv[8];
#pragma unroll
  for (int nt = 0; nt < 8; ++nt) shv[nt] = shb[nt * 16 + lq];
#pragma unroll
  for (int mt = 0; mt < 2; ++mt) {
    int mtile = wq * 2 + mt;
    int h = h0 + (mtile >> 2);
    int w0 = ((mtile & 3) * 16) + quad * 4;
#pragma unroll
    for (int nt = 0; nt < 8; ++nt) {
      int oc = nt * 16 + lq;
      float4 v;
      v.x = fmaxf(acc[mt][nt][0] + shv[nt], 0.f);
      v.y = fmaxf(acc[mt][nt][1] + shv[nt], 0.f);
      v.z = fmaxf(acc[mt][nt][2] + shv[nt], 0.f);
      v.w = fmaxf(acc[mt][nt][3] + shv[nt], 0.f);
      *(float4*)&out[((size_t)b * 128 + oc) * HW + h * 64 + w0] = v;
    }
  }
}

// ---------------------------------------------------------------------------
extern "C" void kernel_launch(void* const* d_in, const int* in_sizes, int n_in,
                              void* d_out, int out_size, void* d_ws, size_t ws_size,
                              hipStream_t stream) {
  const float* x_up   = (const float*)d_in[0];
  const float* x_skip = (const float*)d_in[1];
  const float* kv1_w  = (const float*)d_in[2];
  const float* kv1_b  = (const float*)d_in[3];
  const float* kv2_w  = (const float*)d_in[4];
  const float* kv2_b  = (const float*)d_in[5];
  const float* conv_w = (const float*)d_in[6];
  const float* bn_g   = (const float*)d_in[7];
  const float* bn_b   = (const float*)d_in[8];
  const float* bn_m   = (const float*)d_in[9];
  const float* bn_v   = (const float*)d_in[10];
  float* out = (float*)d_out;

  char* ws = (char*)d_ws;
  const size_t XCATB_B = (size_t)8 * HW * 128 * 2;  // 8.39 MB bf16 n-major
  const size_t KV32_B  = (size_t)8 * 64 * HW * 4;   // 8.39 MB
  const size_t KV16_B  = (size_t)8 * 64 * HW * 2;   // 4.19 MB
  size_t off = 0;
  u16*   xcat = (u16*)(ws + off);   off += XCATB_B;
  float* K2t  = (float*)(ws + off); off += KV32_B;
  float* V2t  = (float*)(ws + off); off += KV32_B;
  u32*   Knm  = (u32*)(ws + off);   off += KV16_B;
  u16*   Vcm  = (u16*)(ws + off);   off += KV16_B;
  float* Mp   = (float*)(ws + off); off += (size_t)32 * 8 * 4096 * 4;
  float* M    = (float*)(ws + off); off += (size_t)8 * 4096 * 4;
  float* A    = (float*)(ws + off); off += (size_t)8 * 4096 * 4;
  u16*   Wg   = (u16*)(ws + off);   off += (size_t)9 * 128 * 128 * 2;
  float* shb  = (float*)(ws + off); off += 128 * 4;

  wcvt<<<576, 256, 0, stream>>>(conv_w, bn_g, bn_b, bn_m, bn_v, Wg, shb);
  kv_proj<<<dim3(64, 8), 256, 0, stream>>>(x_skip, kv1_w, kv1_b, kv2_w, kv2_b,
                                           Knm, Vcm, K2t, V2t);
  attn_mfma<<<dim3(64, 8), 256, 0, stream>>>(x_up, x_skip, (const u16*)Knm, Vcm, xcat);
  chan_gram<<<dim3(32, 8), 256, 0, stream>>>(x_up, K2t, Mp);
  chan_reduce<<<128, 256, 0, stream>>>(Mp, M);
  chan_softmax<<<8, 64, 0, stream>>>(M, A);
  chan_apply<<<dim3(64, 8), 256, 0, stream>>>(V2t, A, x_up, x_skip, xcat);
  conv_mfma<<<dim3(32, 8), 256, 0, stream>>>(xcat, Wg, shb, out);
}

// Round 6
// 279.758 us; speedup vs baseline: 4.7849x; 1.2585x over previous
//
#include <hip/hip_runtime.h>
#include <math.h>

#define HW 4096

typedef __attribute__((ext_vector_type(8))) short bh8;
typedef __attribute__((ext_vector_type(4))) float f32x4;
typedef unsigned int u32;
typedef unsigned short u16;

__device__ __forceinline__ u16 f2bf(float f) {
  union { float f; u32 u; } v; v.f = f;
  u32 u = v.u;
  return (u16)((u + 0x7FFFu + ((u >> 16) & 1u)) >> 16);
}

// ---------------------------------------------------------------------------
// kv projection. Branch 1 (spatial attn): K1 -> bf16 n-major (b,4096,64),
// V1 -> bf16 ch-major (b,64,4096). Branch 2 (channel attn): fp32 ch-major.
// grid (64 nblk, 8 b), block 256
// ---------------------------------------------------------------------------
__global__ __launch_bounds__(256) void kv_proj(
    const float* __restrict__ xs,
    const float* __restrict__ w1, const float* __restrict__ b1,
    const float* __restrict__ w2, const float* __restrict__ b2,
    u32* __restrict__ Knm, u16* __restrict__ Vcm,
    float* __restrict__ K2t, float* __restrict__ V2t) {
  __shared__ float Ss[64][65];
  __shared__ float Ws[128 * 64];
  __shared__ u32 LtK[64][33];  // packed bf16x2 K rows, conflict-free pitch
  const int b = blockIdx.y, n0 = blockIdx.x * 64;
  const int t = threadIdx.x;
  const int lane_n = t & 63, jg = t >> 6;
  const int jbase = jg * 32;
  const float* xsb = xs + (size_t)b * 128 * HW;

  for (int br = 0; br < 2; ++br) {
    const float* W = br ? w2 : w1;
    const float* bias = br ? b2 : b1;
    const float* src = xsb + (br ? 64 * HW : 0);
    __syncthreads();
    for (int s = 0; s < 16; ++s) {
      int ch = s * 4 + jg;
      Ss[ch][lane_n] = src[(size_t)ch * HW + n0 + lane_n];
    }
    for (int i = t; i < 128 * 64; i += 256) Ws[i] = W[i];
    __syncthreads();

    float acc[32];
#pragma unroll
    for (int i = 0; i < 32; ++i) acc[i] = bias[jbase + i];
    for (int ch = 0; ch < 64; ++ch) {
      float s = Ss[ch][lane_n];
#pragma unroll
      for (int i = 0; i < 32; ++i) acc[i] = fmaf(Ws[(jbase + i) * 64 + ch], s, acc[i]);
    }

    if (br == 0) {
      if (jg < 2) {  // K channels jbase..jbase+31 -> pack to LDS
#pragma unroll
        for (int i2 = 0; i2 < 16; ++i2) {
          u32 p = (u32)f2bf(acc[2 * i2]) | ((u32)f2bf(acc[2 * i2 + 1]) << 16);
          LtK[lane_n][jg * 16 + i2] = p;
        }
      } else {  // V channels (jbase-64)..+31 -> bf16 ch-major global
#pragma unroll
        for (int i = 0; i < 32; ++i) {
          int ch = jbase - 64 + i;
          Vcm[((size_t)b * 64 + ch) * HW + n0 + lane_n] = f2bf(acc[i]);
        }
      }
      __syncthreads();
      // coalesced n-major K write: rows of 32 uints (64 bf16)
#pragma unroll
      for (int p = 0; p < 8; ++p) {
        int idx = p * 256 + t;
        int n = idx >> 5, cc = idx & 31;
        Knm[((size_t)b * HW + n0 + n) * 32 + cc] = LtK[n][cc];
      }
    } else {
      float* Kt = K2t + (size_t)b * 64 * HW;
      float* Vt = V2t + (size_t)b * 64 * HW;
#pragma unroll
      for (int i = 0; i < 32; ++i) {
        int j = jbase + i;
        float* dst = (j < 64) ? (Kt + (size_t)j * HW) : (Vt + (size_t)(j - 64) * HW);
        dst[n0 + lane_n] = acc[i];
      }
    }
  }
}

// ---------------------------------------------------------------------------
// MFMA flash attention, barrier-free K-loop. Key-sliced waves: each wave owns
// a 32-key slice per 128-key tile. K/V fragments loaded DIRECTLY global->VGPR
// (no LDS staging, no __syncthreads in the loop) with 2-deep register double
// buffering. exp(S-12) (no max tracking; shift cancels in O/l). P roundtrips
// through wave-private LDS (C-layout -> A-layout). Cross-wave reduce at end.
// grid (64 qblk, 8 b), block 256
// ---------------------------------------------------------------------------
__device__ __forceinline__ void attn_step(
    const bh8* kf, const bh8* vf, const bh8 (&qb)[4][2],
    f32x4 (&O)[4][4], float (&lsum)[4], u16* Pw, int lq, int quad) {
  f32x4 S[2][4];
#pragma unroll
  for (int mt = 0; mt < 2; ++mt)
#pragma unroll
    for (int nt = 0; nt < 4; ++nt) {
      f32x4 a = (f32x4)(0.f);
      a = __builtin_amdgcn_mfma_f32_16x16x32_bf16(kf[mt * 2 + 0], qb[nt][0], a, 0, 0, 0);
      a = __builtin_amdgcn_mfma_f32_16x16x32_bf16(kf[mt * 2 + 1], qb[nt][1], a, 0, 0, 0);
      S[mt][nt] = a;
    }
#pragma unroll
  for (int mt = 0; mt < 2; ++mt)
#pragma unroll
    for (int nt = 0; nt < 4; ++nt) {
      float p0 = __expf(S[mt][nt][0] - 12.f);
      float p1 = __expf(S[mt][nt][1] - 12.f);
      float p2 = __expf(S[mt][nt][2] - 12.f);
      float p3 = __expf(S[mt][nt][3] - 12.f);
      lsum[nt] += (p0 + p1) + (p2 + p3);
      u32 lo = (u32)f2bf(p0) | ((u32)f2bf(p1) << 16);
      u32 hi = (u32)f2bf(p2) | ((u32)f2bf(p3) << 16);
      *(uint2*)&Pw[(nt * 16 + lq) * 36 + mt * 16 + quad * 4] = make_uint2(lo, hi);
    }
#pragma unroll
  for (int nt = 0; nt < 4; ++nt) {
    bh8 pb = *(const bh8*)&Pw[(nt * 16 + lq) * 36 + quad * 8];
#pragma unroll
    for (int ct = 0; ct < 4; ++ct)
      O[ct][nt] = __builtin_amdgcn_mfma_f32_16x16x32_bf16(vf[ct], pb, O[ct][nt], 0, 0, 0);
  }
}

#define LOADKV(KB, KF, VF)                                            \
  do {                                                                \
    const int n0_ = (KB) * 128;                                       \
    const u16* kr_ = Kb + (size_t)(n0_ + wb + lq) * 64 + quad * 8;    \
    KF[0] = *(const bh8*)(kr_);                                       \
    KF[1] = *(const bh8*)(kr_ + 32);                                  \
    KF[2] = *(const bh8*)(kr_ + 1024);                                \
    KF[3] = *(const bh8*)(kr_ + 1056);                                \
    const u16* vr_ = Vb + (size_t)lq * HW + n0_ + wb + quad * 8;      \
    VF[0] = *(const bh8*)(vr_);                                       \
    VF[1] = *(const bh8*)(vr_ + 16 * HW);                             \
    VF[2] = *(const bh8*)(vr_ + 32 * HW);                             \
    VF[3] = *(const bh8*)(vr_ + 48 * HW);                             \
  } while (0)

__global__ __launch_bounds__(256, 2) void attn_mfma(
    const float* __restrict__ xu, const float* __restrict__ xs,
    const u16* __restrict__ Knm, const u16* __restrict__ Vcm,
    u16* __restrict__ xcat) {
  __shared__ __align__(16) u16 SMEM[18432];  // 36864 B
  const int b = blockIdx.y, q0 = blockIdx.x * 64;
  const int t = threadIdx.x;
  const int wq = t >> 6, lane = t & 63, lq = lane & 15, quad = lane >> 4;
  const int wb = wq * 32;  // wave's key-slice base within a 128-key tile
  const float* xub = xu + (size_t)b * 128 * HW;
  const float* xsb = xs + (size_t)b * 128 * HW;
  const u16* Kb = Knm + (size_t)b * HW * 64;
  const u16* Vb = Vcm + (size_t)b * 64 * HW;
  u16* Pw = SMEM + wq * 64 * 36;  // wave-private P (q,k) tile

  // Q B-fragments: all 64 q x 64 ch per wave (B[n=q][k=ch])
  bh8 qb[4][2];
#pragma unroll
  for (int nt = 0; nt < 4; ++nt)
#pragma unroll
    for (int s = 0; s < 2; ++s)
#pragma unroll
      for (int j = 0; j < 8; ++j) {
        int ch = s * 32 + quad * 8 + j;
        qb[nt][s][j] = (short)f2bf(xub[(size_t)ch * HW + q0 + nt * 16 + lq]);
      }

  f32x4 O[4][4];  // [ct: ch-tile][nt: q-tile], C: row=ch_local, col=q_local
#pragma unroll
  for (int ct = 0; ct < 4; ++ct)
#pragma unroll
    for (int nt = 0; nt < 4; ++nt) O[ct][nt] = (f32x4)(0.f);
  float lsum[4] = {0.f, 0.f, 0.f, 0.f};

  bh8 kfa[4], vfa[4], kfb[4], vfb[4];
  LOADKV(0, kfa, vfa);
  for (int kb = 0; kb < 32; kb += 2) {
    LOADKV(kb + 1, kfb, vfb);
    attn_step(kfa, vfa, qb, O, lsum, Pw, lq, quad);
    if (kb + 2 < 32) LOADKV(kb + 2, kfa, vfa);
    attn_step(kfb, vfb, qb, O, lsum, Pw, lq, quad);
  }

  // ---- epilogue: cross-wave reduce, normalize, shortcut, bf16 store ----
#pragma unroll
  for (int nt = 0; nt < 4; ++nt) {
    lsum[nt] += __shfl_xor(lsum[nt], 16);
    lsum[nt] += __shfl_xor(lsum[nt], 32);
  }
  __syncthreads();  // all waves done with their Pw before SMEM reuse
  float* Posc = (float*)SMEM;            // [4 waves][32 ch][68 q] = 34816 B
  float* Lred = (float*)(SMEM + 17408);  // [4 waves][4 nt][16 lq] = 1024 B
  if (quad == 0) {
#pragma unroll
    for (int nt = 0; nt < 4; ++nt) Lred[(wq * 4 + nt) * 16 + lq] = lsum[nt];
  }

  const int q = t & 63, cg = t >> 6;
#pragma unroll
  for (int rh = 0; rh < 2; ++rh) {
    if (rh) __syncthreads();  // previous half's readers done
#pragma unroll
    for (int c2 = 0; c2 < 2; ++c2)
#pragma unroll
      for (int nt = 0; nt < 4; ++nt)
#pragma unroll
        for (int r = 0; r < 4; ++r)
          Posc[(wq * 32 + c2 * 16 + quad * 4 + r) * 68 + nt * 16 + lq] =
              O[rh * 2 + c2][nt][r];
    __syncthreads();
    float li = 0.f;
#pragma unroll
    for (int w2 = 0; w2 < 4; ++w2) li += Lred[w2 * 64 + q];
    float inv = 1.f / li;
    u16 h[8];
#pragma unroll
    for (int i = 0; i < 8; ++i) {
      int chl = cg * 8 + i;
      float s = 0.f;
#pragma unroll
      for (int w2 = 0; w2 < 4; ++w2) s += Posc[(w2 * 32 + chl) * 68 + q];
      int ch = rh * 32 + chl;
      size_t g = (size_t)ch * HW + q0 + q;
      h[i] = f2bf(s * inv + xub[g] + xsb[g]);
    }
    u32 pk[4];
#pragma unroll
    for (int j = 0; j < 4; ++j) pk[j] = (u32)h[2 * j] | ((u32)h[2 * j + 1] << 16);
    u16* ob = xcat + ((size_t)b * HW + q0 + q) * 128 + rh * 32 + cg * 8;
    *(uint4*)ob = make_uint4(pk[0], pk[1], pk[2], pk[3]);
  }
}

// ---------------------------------------------------------------------------
// Channel gram partials: Mp[chunk][b][c][d] = sum over 128 n of u2[c,n]k2[d,n]
// grid (32 nchunk, 8 b), block 256.
// ---------------------------------------------------------------------------
__global__ __launch_bounds__(256) void chan_gram(
    const float* __restrict__ xu, const float* __restrict__ K2t,
    float* __restrict__ Mp) {
  __shared__ float Us[64][65], Ksm[64][65];
  const int b = blockIdx.y, n0 = blockIdx.x * 128;
  const int t = threadIdx.x, c = t & 63, dg = t >> 6;
  const float* ub = xu + ((size_t)b * 128 + 64) * HW;
  const float* kb = K2t + (size_t)b * 64 * HW;
  float acc[16];
#pragma unroll
  for (int i = 0; i < 16; ++i) acc[i] = 0.f;
  for (int s = 0; s < 2; ++s) {
    int nn = n0 + s * 64;
    __syncthreads();
    for (int r = 0; r < 16; ++r) {
      int row = r * 4 + dg;
      Us[row][c] = ub[(size_t)row * HW + nn + c];
      Ksm[row][c] = kb[(size_t)row * HW + nn + c];
    }
    __syncthreads();
    for (int n = 0; n < 64; ++n) {
      float u = Us[c][n];
#pragma unroll
      for (int i = 0; i < 16; ++i) acc[i] = fmaf(Ksm[dg * 16 + i][n], u, acc[i]);
    }
  }
  float* dst = Mp + ((size_t)blockIdx.x * 8 + b) * 4096 + c * 64 + dg * 16;
#pragma unroll
  for (int i = 0; i < 16; ++i) dst[i] = acc[i];
}

// reduce 32 chunk-partials -> M. grid 128, block 256.
__global__ void chan_reduce(const float* __restrict__ Mp, float* __restrict__ M) {
  int idx = blockIdx.x * 256 + threadIdx.x;  // 32768 cells
  float s = 0.f;
  for (int ch = 0; ch < 32; ++ch) s += Mp[(size_t)ch * 32768 + idx];
  M[idx] = s;
}

// ---------------------------------------------------------------------------
// chan_apply with fused softmax: A = softmax_c(M[b]) computed in-block, then
// cout[n][d] = sum_c v2[n][c]*A[c][d]; + shortcut2; bf16 n-major store.
// grid (64 nblk, 8 b), block 256
// ---------------------------------------------------------------------------
__global__ __launch_bounds__(256) void chan_apply(
    const float* __restrict__ V2t, const float* __restrict__ M,
    const float* __restrict__ xu, const float* __restrict__ xs,
    u16* __restrict__ xcat) {
  __shared__ float Vsm[64][65];
  __shared__ float As[64][65];
  __shared__ float red1[4][64], red2[4][64];
  const int b = blockIdx.y, n0 = blockIdx.x * 64, t = threadIdx.x;
  const int lane = t & 63, dg = t >> 6;
  const float* Vb = V2t + (size_t)b * 64 * HW;
  for (int s = 0; s < 16; ++s) {
    int c = s * 4 + dg;
    Vsm[lane][c] = Vb[(size_t)c * HW + n0 + lane];
  }
  for (int idx = t; idx < 4096; idx += 256) As[idx >> 6][idx & 63] = M[b * 4096 + idx];
  __syncthreads();
  // softmax over c per d=lane; this thread owns c in [dg*16, dg*16+16)
  float mx = -1e30f;
#pragma unroll
  for (int i = 0; i < 16; ++i) mx = fmaxf(mx, As[dg * 16 + i][lane]);
  red1[dg][lane] = mx;
  __syncthreads();
  mx = fmaxf(fmaxf(red1[0][lane], red1[1][lane]), fmaxf(red1[2][lane], red1[3][lane]));
  float se = 0.f;
#pragma unroll
  for (int i = 0; i < 16; ++i) {
    float e = __expf(As[dg * 16 + i][lane] - mx);
    As[dg * 16 + i][lane] = e;  // own cells only
    se += e;
  }
  red2[dg][lane] = se;
  __syncthreads();

  float acc[16];
#pragma unroll
  for (int i = 0; i < 16; ++i) acc[i] = 0.f;
  for (int c = 0; c < 64; ++c) {
    float v = Vsm[lane][c];
#pragma unroll
    for (int i = 0; i < 16; ++i) acc[i] = fmaf(v, As[c][dg * 16 + i], acc[i]);
  }
  const float* xub = xu + ((size_t)b * 128 + 64) * HW;
  const float* xsb = xs + ((size_t)b * 128 + 64) * HW;
  const int n = n0 + lane;
  u16 hv[16];
#pragma unroll
  for (int i = 0; i < 16; ++i) {
    int d = dg * 16 + i;
    float sm = red2[0][d] + red2[1][d] + red2[2][d] + red2[3][d];
    hv[i] = f2bf(acc[i] / sm + xub[(size_t)d * HW + n] + xsb[(size_t)d * HW + n]);
  }
  u32 pk[8];
#pragma unroll
  for (int j = 0; j < 8; ++j) pk[j] = (u32)hv[2 * j] | ((u32)hv[2 * j + 1] << 16);
  u16* ob = xcat + ((size_t)b * HW + n) * 128 + 64 + dg * 16;
  *(uint4*)(ob) = make_uint4(pk[0], pk[1], pk[2], pk[3]);
  *(uint4*)(ob + 8) = make_uint4(pk[4], pk[5], pk[6], pk[7]);
}

// ---------------------------------------------------------------------------
// Weight convert: conv_w (oc, ic, 3, 3) fp32 -> Wg[tap][oc][ic] bf16 with BN
// scale folded in; shb[oc] = BN shift. grid 576, block 256.
// ---------------------------------------------------------------------------
__global__ void wcvt(const float* __restrict__ w, const float* __restrict__ gamma,
                     const float* __restrict__ beta, const float* __restrict__ mean,
                     const float* __restrict__ var,
                     u16* __restrict__ Wg, float* __restrict__ shb) {
  int idx = blockIdx.x * 256 + threadIdx.x;
  if (idx < 147456) {
    int tap = idx >> 14;
    int oc = (idx >> 7) & 127;
    int ic = idx & 127;
    float sc = gamma[oc] * rsqrtf(var[oc] + 1e-5f);
    Wg[idx] = f2bf(w[((size_t)(oc * 128 + ic)) * 9 + tap] * sc);
  }
  if (idx < 128) {
    float sc = gamma[idx] * rsqrtf(var[idx] + 1e-5f);
    shb[idx] = beta[idx] - mean[idx] * sc;
  }
}

// ---------------------------------------------------------------------------
// Implicit-GEMM 3x3 conv via bf16 MFMA + fused BN(folded) + ReLU.
// Block: 256 thr = 4 waves. Tile: 128 spatial (2 h-rows x 64 w) x 128 oc.
// grid (32 hblk, 8 b), block 256
// ---------------------------------------------------------------------------
__global__ __launch_bounds__(256) void conv_mfma(
    const u16* __restrict__ X, const u16* __restrict__ Wg,
    const float* __restrict__ shb, float* __restrict__ out) {
  __shared__ __align__(16) u16 In[4 * 66 * 136];
  __shared__ __align__(16) u16 Wt[2][128 * 136];
  const int b = blockIdx.y, h0 = blockIdx.x * 2;
  const int t = threadIdx.x;
  const int wq = t >> 6, lane = t & 63, lq = lane & 15, quad = lane >> 4;
  const u16* Xb = X + (size_t)b * HW * 128;

  // zero w-halo cells (iw = 0 and 65 for each ih)
  if (t < 128) {
    int ih = t >> 5, iwsel = (t >> 4) & 1, ck = t & 15;
    int iw = iwsel ? 65 : 0;
    *(uint4*)&In[(ih * 66 + iw) * 136 + ck * 8] = make_uint4(0, 0, 0, 0);
  }
  // stage input rows (zero h-halo out of range)
  for (int ih = 0; ih < 4; ++ih) {
    int h = h0 - 1 + ih;
    bool ok = (h >= 0 && h < 64);
    const u16* src = Xb + (size_t)h * 64 * 128;
#pragma unroll
    for (int p = 0; p < 4; ++p) {
      int idx = p * 256 + t;
      int row = idx >> 4, ck = idx & 15;
      uint4 d = make_uint4(0, 0, 0, 0);
      if (ok) d = *(const uint4*)(src + (size_t)row * 128 + ck * 8);
      *(uint4*)&In[(ih * 66 + 1 + row) * 136 + ck * 8] = d;
    }
  }
  // stage tap-0 weights into buffer 0 (128 oc x 16 chunks = 2048 uint4 = 8 passes)
  {
    const u16* src = Wg;
#pragma unroll
    for (int p = 0; p < 8; ++p) {
      int idx = p * 256 + t;
      int oc = idx >> 4, ck = idx & 15;
      uint4 d = *(const uint4*)(src + oc * 128 + ck * 8);
      *(uint4*)&Wt[0][oc * 136 + ck * 8] = d;
    }
  }
  __syncthreads();

  f32x4 acc[2][8];
#pragma unroll
  for (int mt = 0; mt < 2; ++mt)
#pragma unroll
    for (int nt = 0; nt < 8; ++nt) acc[mt][nt] = (f32x4)(0.f);

  for (int tap = 0; tap < 9; ++tap) {
    const int cur = tap & 1;
    if (tap < 8) {  // prefetch next tap into the other buffer
      const u16* src = Wg + (size_t)(tap + 1) * 128 * 128;
#pragma unroll
      for (int p = 0; p < 8; ++p) {
        int idx = p * 256 + t;
        int oc = idx >> 4, ck = idx & 15;
        uint4 d = *(const uint4*)(src + oc * 128 + ck * 8);
        *(uint4*)&Wt[cur ^ 1][oc * 136 + ck * 8] = d;
      }
    }
    const int dh = tap / 3, dw = tap - 3 * dh;
    const u16* Wc = &Wt[cur][0];
#pragma unroll
    for (int c = 0; c < 4; ++c) {
      bh8 bf[8];
#pragma unroll
      for (int nt = 0; nt < 8; ++nt)
        bf[nt] = *(const bh8*)&Wc[(nt * 16 + lq) * 136 + c * 32 + quad * 8];
#pragma unroll
      for (int mt = 0; mt < 2; ++mt) {
        int s = (wq * 2 + mt) * 16 + lq;
        int ih = (s >> 6) + dh, iw = (s & 63) + dw;
        bh8 af = *(const bh8*)&In[(ih * 66 + iw) * 136 + c * 32 + quad * 8];
#pragma unroll
        for (int nt = 0; nt < 8; ++nt)
          acc[mt][nt] = __builtin_amdgcn_mfma_f32_16x16x32_bf16(af, bf[nt], acc[mt][nt], 0, 0, 0);
      }
    }
    __syncthreads();
  }

  // epilogue: +bias, ReLU, dense float4 stores
  float shv[8];
#pragma unroll
  for (int nt = 0; nt < 8; ++nt) shv[nt] = shb[nt * 16 + lq];
#pragma unroll
  for (int mt = 0; mt < 2; ++mt) {
    int mtile = wq * 2 + mt;
    int h = h0 + (mtile >> 2);
    int w0 = ((mtile & 3) * 16) + quad * 4;
#pragma unroll
    for (int nt = 0; nt < 8; ++nt) {
      int oc = nt * 16 + lq;
      float4 v;
      v.x = fmaxf(acc[mt][nt][0] + shv[nt], 0.f);
      v.y = fmaxf(acc[mt][nt][1] + shv[nt], 0.f);
      v.z = fmaxf(acc[mt][nt][2] + shv[nt], 0.f);
      v.w = fmaxf(acc[mt][nt][3] + shv[nt], 0.f);
      *(float4*)&out[((size_t)b * 128 + oc) * HW + h * 64 + w0] = v;
    }
  }
}

// ---------------------------------------------------------------------------
extern "C" void kernel_launch(void* const* d_in, const int* in_sizes, int n_in,
                              void* d_out, int out_size, void* d_ws, size_t ws_size,
                              hipStream_t stream) {
  const float* x_up   = (const float*)d_in[0];
  const float* x_skip = (const float*)d_in[1];
  const float* kv1_w  = (const float*)d_in[2];
  const float* kv1_b  = (const float*)d_in[3];
  const float* kv2_w  = (const float*)d_in[4];
  const float* kv2_b  = (const float*)d_in[5];
  const float* conv_w = (const float*)d_in[6];
  const float* bn_g   = (const float*)d_in[7];
  const float* bn_b   = (const float*)d_in[8];
  const float* bn_m   = (const float*)d_in[9];
  const float* bn_v   = (const float*)d_in[10];
  float* out = (float*)d_out;

  char* ws = (char*)d_ws;
  const size_t XCATB_B = (size_t)8 * HW * 128 * 2;  // 8.39 MB bf16 n-major
  const size_t KV32_B  = (size_t)8 * 64 * HW * 4;   // 8.39 MB
  const size_t KV16_B  = (size_t)8 * 64 * HW * 2;   // 4.19 MB
  size_t off = 0;
  u16*   xcat = (u16*)(ws + off);   off += XCATB_B;
  float* K2t  = (float*)(ws + off); off += KV32_B;
  float* V2t  = (float*)(ws + off); off += KV32_B;
  u32*   Knm  = (u32*)(ws + off);   off += KV16_B;
  u16*   Vcm  = (u16*)(ws + off);   off += KV16_B;
  float* Mp   = (float*)(ws + off); off += (size_t)32 * 8 * 4096 * 4;
  float* M    = (float*)(ws + off); off += (size_t)8 * 4096 * 4;
  u16*   Wg   = (u16*)(ws + off);   off += (size_t)9 * 128 * 128 * 2;
  float* shb  = (float*)(ws + off); off += 128 * 4;

  wcvt<<<576, 256, 0, stream>>>(conv_w, bn_g, bn_b, bn_m, bn_v, Wg, shb);
  kv_proj<<<dim3(64, 8), 256, 0, stream>>>(x_skip, kv1_w, kv1_b, kv2_w, kv2_b,
                                           Knm, Vcm, K2t, V2t);
  attn_mfma<<<dim3(64, 8), 256, 0, stream>>>(x_up, x_skip, (const u16*)Knm, Vcm, xcat);
  chan_gram<<<dim3(32, 8), 256, 0, stream>>>(x_up, K2t, Mp);
  chan_reduce<<<128, 256, 0, stream>>>(Mp, M);
  chan_apply<<<dim3(64, 8), 256, 0, stream>>>(V2t, M, x_up, x_skip, xcat);
  conv_mfma<<<dim3(32, 8), 256, 0, stream>>>(xcat, Wg, shb, out);
}

// Round 7
// 276.037 us; speedup vs baseline: 4.8494x; 1.0135x over previous
//
#include <hip/hip_runtime.h>
#include <math.h>

#define HW 4096

typedef __attribute__((ext_vector_type(8))) short bh8;
typedef __attribute__((ext_vector_type(4))) float f32x4;
typedef unsigned int u32;
typedef unsigned short u16;

__device__ __forceinline__ u16 f2bf(float f) {
  union { float f; u32 u; } v; v.f = f;
  u32 u = v.u;
  return (u16)((u + 0x7FFFu + ((u >> 16) & 1u)) >> 16);
}

// ---------------------------------------------------------------------------
// kv projection (+ fused conv-weight convert prologue).
// Branch 1 (spatial attn): K1 -> bf16 n-major (b,4096,64), V1 -> bf16
// ch-major (b,64,4096). Branch 2 (channel attn): fp32 ch-major.
// grid (64 nblk, 8 b), block 256
// ---------------------------------------------------------------------------
__global__ __launch_bounds__(256) void kv_proj(
    const float* __restrict__ xs,
    const float* __restrict__ w1, const float* __restrict__ b1,
    const float* __restrict__ w2, const float* __restrict__ b2,
    u32* __restrict__ Knm, u16* __restrict__ Vcm,
    float* __restrict__ K2t, float* __restrict__ V2t,
    const float* __restrict__ cw, const float* __restrict__ gamma,
    const float* __restrict__ beta, const float* __restrict__ mean,
    const float* __restrict__ var, u16* __restrict__ Wg,
    float* __restrict__ shb) {
  __shared__ float Ss[64][65];
  __shared__ float Ws[128 * 64];
  __shared__ u32 LtK[64][33];  // packed bf16x2 K rows, conflict-free pitch
  const int b = blockIdx.y, n0 = blockIdx.x * 64;
  const int t = threadIdx.x;
  const int lane_n = t & 63, jg = t >> 6;
  const int jbase = jg * 32;
  const float* xsb = xs + (size_t)b * 128 * HW;

  // ---- fused wcvt: conv_w (oc,ic,3,3) -> Wg[tap][oc][ic] bf16, BN folded ----
  {
    int gid = (blockIdx.y * 64 + blockIdx.x) * 256 + t;  // 0..131071
    for (int i = gid; i < 147456; i += 131072) {
      int tap = i >> 14, oc = (i >> 7) & 127, ic = i & 127;
      float sc = gamma[oc] * rsqrtf(var[oc] + 1e-5f);
      Wg[i] = f2bf(cw[((size_t)(oc * 128 + ic)) * 9 + tap] * sc);
    }
    if (gid < 128) {
      float sc = gamma[gid] * rsqrtf(var[gid] + 1e-5f);
      shb[gid] = beta[gid] - mean[gid] * sc;
    }
  }

  for (int br = 0; br < 2; ++br) {
    const float* W = br ? w2 : w1;
    const float* bias = br ? b2 : b1;
    const float* src = xsb + (br ? 64 * HW : 0);
    __syncthreads();
    for (int s = 0; s < 16; ++s) {
      int ch = s * 4 + jg;
      Ss[ch][lane_n] = src[(size_t)ch * HW + n0 + lane_n];
    }
    for (int i = t; i < 128 * 64; i += 256) Ws[i] = W[i];
    __syncthreads();

    float acc[32];
#pragma unroll
    for (int i = 0; i < 32; ++i) acc[i] = bias[jbase + i];
    for (int ch = 0; ch < 64; ++ch) {
      float s = Ss[ch][lane_n];
#pragma unroll
      for (int i = 0; i < 32; ++i) acc[i] = fmaf(Ws[(jbase + i) * 64 + ch], s, acc[i]);
    }

    if (br == 0) {
      if (jg < 2) {  // K channels jbase..jbase+31 -> pack to LDS
#pragma unroll
        for (int i2 = 0; i2 < 16; ++i2) {
          u32 p = (u32)f2bf(acc[2 * i2]) | ((u32)f2bf(acc[2 * i2 + 1]) << 16);
          LtK[lane_n][jg * 16 + i2] = p;
        }
      } else {  // V channels (jbase-64)..+31 -> bf16 ch-major global
#pragma unroll
        for (int i = 0; i < 32; ++i) {
          int ch = jbase - 64 + i;
          Vcm[((size_t)b * 64 + ch) * HW + n0 + lane_n] = f2bf(acc[i]);
        }
      }
      __syncthreads();
      // coalesced n-major K write: rows of 32 uints (64 bf16)
#pragma unroll
      for (int p = 0; p < 8; ++p) {
        int idx = p * 256 + t;
        int n = idx >> 5, cc = idx & 31;
        Knm[((size_t)b * HW + n0 + n) * 32 + cc] = LtK[n][cc];
      }
    } else {
      float* Kt = K2t + (size_t)b * 64 * HW;
      float* Vt = V2t + (size_t)b * 64 * HW;
#pragma unroll
      for (int i = 0; i < 32; ++i) {
        int j = jbase + i;
        float* dst = (j < 64) ? (Kt + (size_t)j * HW) : (Vt + (size_t)(j - 64) * HW);
        dst[n0 + lane_n] = acc[i];
      }
    }
  }
}

// ---------------------------------------------------------------------------
// MFMA flash attention, barrier-free K-loop, key-sliced waves, direct
// global->VGPR K/V loads, 2-deep register dbuf AND double-buffered P LDS
// (each unrolled step uses its own P region -> no write-after-read serial
// dependency between steps). exp(S-12) without max tracking. P packed via
// v_perm_b32 (round-half-up bf16). grid (64 qblk, 8 b), block 256
// ---------------------------------------------------------------------------
__device__ __forceinline__ void attn_step(
    const bh8* kf, const bh8* vf, const bh8 (&qb)[4][2],
    f32x4 (&O)[4][4], float (&lsum)[4], u16* Pw, int lq, int quad) {
  f32x4 S[2][4];
#pragma unroll
  for (int mt = 0; mt < 2; ++mt)
#pragma unroll
    for (int nt = 0; nt < 4; ++nt) {
      f32x4 a = (f32x4)(0.f);
      a = __builtin_amdgcn_mfma_f32_16x16x32_bf16(kf[mt * 2 + 0], qb[nt][0], a, 0, 0, 0);
      a = __builtin_amdgcn_mfma_f32_16x16x32_bf16(kf[mt * 2 + 1], qb[nt][1], a, 0, 0, 0);
      S[mt][nt] = a;
    }
#pragma unroll
  for (int mt = 0; mt < 2; ++mt)
#pragma unroll
    for (int nt = 0; nt < 4; ++nt) {
      float p0 = __expf(S[mt][nt][0] - 12.f);
      float p1 = __expf(S[mt][nt][1] - 12.f);
      float p2 = __expf(S[mt][nt][2] - 12.f);
      float p3 = __expf(S[mt][nt][3] - 12.f);
      lsum[nt] += (p0 + p1) + (p2 + p3);
      u32 lo = __builtin_amdgcn_perm(__float_as_uint(p1) + 0x8000u,
                                     __float_as_uint(p0) + 0x8000u, 0x07060302u);
      u32 hi = __builtin_amdgcn_perm(__float_as_uint(p3) + 0x8000u,
                                     __float_as_uint(p2) + 0x8000u, 0x07060302u);
      *(uint2*)&Pw[(nt * 16 + lq) * 36 + mt * 16 + quad * 4] = make_uint2(lo, hi);
    }
#pragma unroll
  for (int nt = 0; nt < 4; ++nt) {
    bh8 pb = *(const bh8*)&Pw[(nt * 16 + lq) * 36 + quad * 8];
#pragma unroll
    for (int ct = 0; ct < 4; ++ct)
      O[ct][nt] = __builtin_amdgcn_mfma_f32_16x16x32_bf16(vf[ct], pb, O[ct][nt], 0, 0, 0);
  }
}

#define LOADKV(KB, KF, VF)                                            \
  do {                                                                \
    const int n0_ = (KB) * 128;                                       \
    const u16* kr_ = Kb + (size_t)(n0_ + wb + lq) * 64 + quad * 8;    \
    KF[0] = *(const bh8*)(kr_);                                       \
    KF[1] = *(const bh8*)(kr_ + 32);                                  \
    KF[2] = *(const bh8*)(kr_ + 1024);                                \
    KF[3] = *(const bh8*)(kr_ + 1056);                                \
    const u16* vr_ = Vb + (size_t)lq * HW + n0_ + wb + quad * 8;      \
    VF[0] = *(const bh8*)(vr_);                                       \
    VF[1] = *(const bh8*)(vr_ + 16 * HW);                             \
    VF[2] = *(const bh8*)(vr_ + 32 * HW);                             \
    VF[3] = *(const bh8*)(vr_ + 48 * HW);                             \
  } while (0)

__global__ __launch_bounds__(256, 2) void attn_mfma(
    const float* __restrict__ xu, const float* __restrict__ xs,
    const u16* __restrict__ Knm, const u16* __restrict__ Vcm,
    u16* __restrict__ xcat) {
  __shared__ __align__(16) u16 SMEM[18432];  // 36864 B
  const int b = blockIdx.y, q0 = blockIdx.x * 64;
  const int t = threadIdx.x;
  const int wq = t >> 6, lane = t & 63, lq = lane & 15, quad = lane >> 4;
  const int wb = wq * 32;  // wave's key-slice base within a 128-key tile
  const float* xub = xu + (size_t)b * 128 * HW;
  const float* xsb = xs + (size_t)b * 128 * HW;
  const u16* Kb = Knm + (size_t)b * HW * 64;
  const u16* Vb = Vcm + (size_t)b * 64 * HW;
  u16* Pw0 = SMEM + wq * 64 * 36;         // step-a P buffer
  u16* Pw1 = SMEM + 9216 + wq * 64 * 36;  // step-b P buffer

  // Q B-fragments: all 64 q x 64 ch per wave (B[n=q][k=ch])
  bh8 qb[4][2];
#pragma unroll
  for (int nt = 0; nt < 4; ++nt)
#pragma unroll
    for (int s = 0; s < 2; ++s)
#pragma unroll
      for (int j = 0; j < 8; ++j) {
        int ch = s * 32 + quad * 8 + j;
        qb[nt][s][j] = (short)f2bf(xub[(size_t)ch * HW + q0 + nt * 16 + lq]);
      }

  f32x4 O[4][4];  // [ct: ch-tile][nt: q-tile], C: row=ch_local, col=q_local
#pragma unroll
  for (int ct = 0; ct < 4; ++ct)
#pragma unroll
    for (int nt = 0; nt < 4; ++nt) O[ct][nt] = (f32x4)(0.f);
  float lsum[4] = {0.f, 0.f, 0.f, 0.f};

  bh8 kfa[4], vfa[4], kfb[4], vfb[4];
  LOADKV(0, kfa, vfa);
  for (int kb = 0; kb < 32; kb += 2) {
    LOADKV(kb + 1, kfb, vfb);
    attn_step(kfa, vfa, qb, O, lsum, Pw0, lq, quad);
    if (kb + 2 < 32) LOADKV(kb + 2, kfa, vfa);
    attn_step(kfb, vfb, qb, O, lsum, Pw1, lq, quad);
  }

  // ---- epilogue: cross-wave reduce, normalize, shortcut, bf16 store ----
#pragma unroll
  for (int nt = 0; nt < 4; ++nt) {
    lsum[nt] += __shfl_xor(lsum[nt], 16);
    lsum[nt] += __shfl_xor(lsum[nt], 32);
  }
  __syncthreads();  // all waves done with their P buffers before SMEM reuse
  float* Posc = (float*)SMEM;            // [4 waves][32 ch][68 q] = 34816 B
  float* Lred = (float*)(SMEM + 17408);  // [4 waves][4 nt][16 lq] = 1024 B
  if (quad == 0) {
#pragma unroll
    for (int nt = 0; nt < 4; ++nt) Lred[(wq * 4 + nt) * 16 + lq] = lsum[nt];
  }

  const int q = t & 63, cg = t >> 6;
#pragma unroll
  for (int rh = 0; rh < 2; ++rh) {
    if (rh) __syncthreads();  // previous half's readers done
#pragma unroll
    for (int c2 = 0; c2 < 2; ++c2)
#pragma unroll
      for (int nt = 0; nt < 4; ++nt)
#pragma unroll
        for (int r = 0; r < 4; ++r)
          Posc[(wq * 32 + c2 * 16 + quad * 4 + r) * 68 + nt * 16 + lq] =
              O[rh * 2 + c2][nt][r];
    __syncthreads();
    float li = 0.f;
#pragma unroll
    for (int w2 = 0; w2 < 4; ++w2) li += Lred[w2 * 64 + q];
    float inv = 1.f / li;
    u16 h[8];
#pragma unroll
    for (int i = 0; i < 8; ++i) {
      int chl = cg * 8 + i;
      float s = 0.f;
#pragma unroll
      for (int w2 = 0; w2 < 4; ++w2) s += Posc[(w2 * 32 + chl) * 68 + q];
      int ch = rh * 32 + chl;
      size_t g = (size_t)ch * HW + q0 + q;
      h[i] = f2bf(s * inv + xub[g] + xsb[g]);
    }
    u32 pk[4];
#pragma unroll
    for (int j = 0; j < 4; ++j) pk[j] = (u32)h[2 * j] | ((u32)h[2 * j + 1] << 16);
    u16* ob = xcat + ((size_t)b * HW + q0 + q) * 128 + rh * 32 + cg * 8;
    *(uint4*)ob = make_uint4(pk[0], pk[1], pk[2], pk[3]);
  }
}

// ---------------------------------------------------------------------------
// Channel gram partials: Mp[chunk][b][c][d] = sum over 128 n of u2[c,n]k2[d,n]
// grid (32 nchunk, 8 b), block 256.
// ---------------------------------------------------------------------------
__global__ __launch_bounds__(256) void chan_gram(
    const float* __restrict__ xu, const float* __restrict__ K2t,
    float* __restrict__ Mp) {
  __shared__ float Us[64][65], Ksm[64][65];
  const int b = blockIdx.y, n0 = blockIdx.x * 128;
  const int t = threadIdx.x, c = t & 63, dg = t >> 6;
  const float* ub = xu + ((size_t)b * 128 + 64) * HW;
  const float* kb = K2t + (size_t)b * 64 * HW;
  float acc[16];
#pragma unroll
  for (int i = 0; i < 16; ++i) acc[i] = 0.f;
  for (int s = 0; s < 2; ++s) {
    int nn = n0 + s * 64;
    __syncthreads();
    for (int r = 0; r < 16; ++r) {
      int row = r * 4 + dg;
      Us[row][c] = ub[(size_t)row * HW + nn + c];
      Ksm[row][c] = kb[(size_t)row * HW + nn + c];
    }
    __syncthreads();
    for (int n = 0; n < 64; ++n) {
      float u = Us[c][n];
#pragma unroll
      for (int i = 0; i < 16; ++i) acc[i] = fmaf(Ksm[dg * 16 + i][n], u, acc[i]);
    }
  }
  float* dst = Mp + ((size_t)blockIdx.x * 8 + b) * 4096 + c * 64 + dg * 16;
#pragma unroll
  for (int i = 0; i < 16; ++i) dst[i] = acc[i];
}

// reduce 32 chunk-partials -> M. grid 128, block 256.
__global__ void chan_reduce(const float* __restrict__ Mp, float* __restrict__ M) {
  int idx = blockIdx.x * 256 + threadIdx.x;  // 32768 cells
  float s = 0.f;
  for (int ch = 0; ch < 32; ++ch) s += Mp[(size_t)ch * 32768 + idx];
  M[idx] = s;
}

// ---------------------------------------------------------------------------
// chan_apply with fused softmax: A = softmax_c(M[b]) computed in-block, then
// cout[n][d] = sum_c v2[n][c]*A[c][d]; + shortcut2; bf16 n-major store.
// grid (64 nblk, 8 b), block 256
// ---------------------------------------------------------------------------
__global__ __launch_bounds__(256) void chan_apply(
    const float* __restrict__ V2t, const float* __restrict__ M,
    const float* __restrict__ xu, const float* __restrict__ xs,
    u16* __restrict__ xcat) {
  __shared__ float Vsm[64][65];
  __shared__ float As[64][65];
  __shared__ float red1[4][64], red2[4][64];
  const int b = blockIdx.y, n0 = blockIdx.x * 64, t = threadIdx.x;
  const int lane = t & 63, dg = t >> 6;
  const float* Vb = V2t + (size_t)b * 64 * HW;
  for (int s = 0; s < 16; ++s) {
    int c = s * 4 + dg;
    Vsm[lane][c] = Vb[(size_t)c * HW + n0 + lane];
  }
  for (int idx = t; idx < 4096; idx += 256) As[idx >> 6][idx & 63] = M[b * 4096 + idx];
  __syncthreads();
  // softmax over c per d=lane; this thread owns c in [dg*16, dg*16+16)
  float mx = -1e30f;
#pragma unroll
  for (int i = 0; i < 16; ++i) mx = fmaxf(mx, As[dg * 16 + i][lane]);
  red1[dg][lane] = mx;
  __syncthreads();
  mx = fmaxf(fmaxf(red1[0][lane], red1[1][lane]), fmaxf(red1[2][lane], red1[3][lane]));
  float se = 0.f;
#pragma unroll
  for (int i = 0; i < 16; ++i) {
    float e = __expf(As[dg * 16 + i][lane] - mx);
    As[dg * 16 + i][lane] = e;  // own cells only
    se += e;
  }
  red2[dg][lane] = se;
  __syncthreads();

  float acc[16];
#pragma unroll
  for (int i = 0; i < 16; ++i) acc[i] = 0.f;
  for (int c = 0; c < 64; ++c) {
    float v = Vsm[lane][c];
#pragma unroll
    for (int i = 0; i < 16; ++i) acc[i] = fmaf(v, As[c][dg * 16 + i], acc[i]);
  }
  const float* xub = xu + ((size_t)b * 128 + 64) * HW;
  const float* xsb = xs + ((size_t)b * 128 + 64) * HW;
  const int n = n0 + lane;
  u16 hv[16];
#pragma unroll
  for (int i = 0; i < 16; ++i) {
    int d = dg * 16 + i;
    float sm = red2[0][d] + red2[1][d] + red2[2][d] + red2[3][d];
    hv[i] = f2bf(acc[i] / sm + xub[(size_t)d * HW + n] + xsb[(size_t)d * HW + n]);
  }
  u32 pk[8];
#pragma unroll
  for (int j = 0; j < 8; ++j) pk[j] = (u32)hv[2 * j] | ((u32)hv[2 * j + 1] << 16);
  u16* ob = xcat + ((size_t)b * HW + n) * 128 + 64 + dg * 16;
  *(uint4*)(ob) = make_uint4(pk[0], pk[1], pk[2], pk[3]);
  *(uint4*)(ob + 8) = make_uint4(pk[4], pk[5], pk[6], pk[7]);
}

// ---------------------------------------------------------------------------
// Implicit-GEMM 3x3 conv via bf16 MFMA + fused BN(folded) + ReLU.
// Block: 512 thr = 8 waves (2 waves/SIMD). Tile: 128 spatial x 128 oc.
// Wave wq: m-tiles {2*(wq>>1), 2*(wq>>1)+1} x oc-half (wq&1)*64 (4 nt).
// grid (32 hblk, 8 b)
// ---------------------------------------------------------------------------
__global__ __launch_bounds__(512) void conv_mfma(
    const u16* __restrict__ X, const u16* __restrict__ Wg,
    const float* __restrict__ shb, float* __restrict__ out) {
  __shared__ __align__(16) u16 In[4 * 66 * 136];
  __shared__ __align__(16) u16 Wt[2][128 * 136];
  const int b = blockIdx.y, h0 = blockIdx.x * 2;
  const int t = threadIdx.x;
  const int wq = t >> 6, lane = t & 63, lq = lane & 15, quad = lane >> 4;
  const int nb = (wq & 1) * 64;       // oc-half base
  const int mb = (wq >> 1) * 2;       // m-tile pair base
  const u16* Xb = X + (size_t)b * HW * 128;

  // zero w-halo cells (iw = 0 and 65 for each ih)
  if (t < 128) {
    int ih = t >> 5, iwsel = (t >> 4) & 1, ck = t & 15;
    int iw = iwsel ? 65 : 0;
    *(uint4*)&In[(ih * 66 + iw) * 136 + ck * 8] = make_uint4(0, 0, 0, 0);
  }
  // stage input rows (zero h-halo out of range); 512 threads
  for (int ih = 0; ih < 4; ++ih) {
    int h = h0 - 1 + ih;
    bool ok = (h >= 0 && h < 64);
    const u16* src = Xb + (size_t)h * 64 * 128;
#pragma unroll
    for (int p = 0; p < 2; ++p) {
      int idx = p * 512 + t;
      int row = idx >> 4, ck = idx & 15;
      uint4 d = make_uint4(0, 0, 0, 0);
      if (ok) d = *(const uint4*)(src + (size_t)row * 128 + ck * 8);
      *(uint4*)&In[(ih * 66 + 1 + row) * 136 + ck * 8] = d;
    }
  }
  // stage tap-0 weights into buffer 0 (2048 uint4 over 512 threads = 4 passes)
  {
    const u16* src = Wg;
#pragma unroll
    for (int p = 0; p < 4; ++p) {
      int idx = p * 512 + t;
      int oc = idx >> 4, ck = idx & 15;
      uint4 d = *(const uint4*)(src + oc * 128 + ck * 8);
      *(uint4*)&Wt[0][oc * 136 + ck * 8] = d;
    }
  }
  __syncthreads();

  f32x4 acc[2][4];
#pragma unroll
  for (int mt = 0; mt < 2; ++mt)
#pragma unroll
    for (int nt = 0; nt < 4; ++nt) acc[mt][nt] = (f32x4)(0.f);

  for (int tap = 0; tap < 9; ++tap) {
    const int cur = tap & 1;
    if (tap < 8) {  // prefetch next tap into the other buffer
      const u16* src = Wg + (size_t)(tap + 1) * 128 * 128;
#pragma unroll
      for (int p = 0; p < 4; ++p) {
        int idx = p * 512 + t;
        int oc = idx >> 4, ck = idx & 15;
        uint4 d = *(const uint4*)(src + oc * 128 + ck * 8);
        *(uint4*)&Wt[cur ^ 1][oc * 136 + ck * 8] = d;
      }
    }
    const int dh = tap / 3, dw = tap - 3 * dh;
    const u16* Wc = &Wt[cur][0];
#pragma unroll
    for (int c = 0; c < 4; ++c) {
      bh8 bf[4];
#pragma unroll
      for (int nt = 0; nt < 4; ++nt)
        bf[nt] = *(const bh8*)&Wc[(nb + nt * 16 + lq) * 136 + c * 32 + quad * 8];
#pragma unroll
      for (int mt = 0; mt < 2; ++mt) {
        int s = (mb + mt) * 16 + lq;
        int ih = (s >> 6) + dh, iw = (s & 63) + dw;
        bh8 af = *(const bh8*)&In[(ih * 66 + iw) * 136 + c * 32 + quad * 8];
#pragma unroll
        for (int nt = 0; nt < 4; ++nt)
          acc[mt][nt] = __builtin_amdgcn_mfma_f32_16x16x32_bf16(af, bf[nt], acc[mt][nt], 0, 0, 0);
      }
    }
    __syncthreads();
  }

  // epilogue: +bias, ReLU, dense float4 stores
  float shv[4];
#pragma unroll
  for (int nt = 0; nt < 4; ++nt) shv[nt] = shb[nb + nt * 16 + lq];
#pragma unroll
  for (int mt = 0; mt < 2; ++mt) {
    int mtile = mb + mt;
    int h = h0 + (mtile >> 2);
    int w0 = ((mtile & 3) * 16) + quad * 4;
#pragma unroll
    for (int nt = 0; nt < 4; ++nt) {
      int oc = nb + nt * 16 + lq;
      float4 v;
      v.x = fmaxf(acc[mt][nt][0] + shv[nt], 0.f);
      v.y = fmaxf(acc[mt][nt][1] + shv[nt], 0.f);
      v.z = fmaxf(acc[mt][nt][2] + shv[nt], 0.f);
      v.w = fmaxf(acc[mt][nt][3] + shv[nt], 0.f);
      *(float4*)&out[((size_t)b * 128 + oc) * HW + h * 64 + w0] = v;
    }
  }
}

// ---------------------------------------------------------------------------
extern "C" void kernel_launch(void* const* d_in, const int* in_sizes, int n_in,
                              void* d_out, int out_size, void* d_ws, size_t ws_size,
                              hipStream_t stream) {
  const float* x_up   = (const float*)d_in[0];
  const float* x_skip = (const float*)d_in[1];
  const float* kv1_w  = (const float*)d_in[2];
  const float* kv1_b  = (const float*)d_in[3];
  const float* kv2_w  = (const float*)d_in[4];
  const float* kv2_b  = (const float*)d_in[5];
  const float* conv_w = (const float*)d_in[6];
  const float* bn_g   = (const float*)d_in[7];
  const float* bn_b   = (const float*)d_in[8];
  const float* bn_m   = (const float*)d_in[9];
  const float* bn_v   = (const float*)d_in[10];
  float* out = (float*)d_out;

  char* ws = (char*)d_ws;
  const size_t XCATB_B = (size_t)8 * HW * 128 * 2;  // 8.39 MB bf16 n-major
  const size_t KV32_B  = (size_t)8 * 64 * HW * 4;   // 8.39 MB
  const size_t KV16_B  = (size_t)8 * 64 * HW * 2;   // 4.19 MB
  size_t off = 0;
  u16*   xcat = (u16*)(ws + off);   off += XCATB_B;
  float* K2t  = (float*)(ws + off); off += KV32_B;
  float* V2t  = (float*)(ws + off); off += KV32_B;
  u32*   Knm  = (u32*)(ws + off);   off += KV16_B;
  u16*   Vcm  = (u16*)(ws + off);   off += KV16_B;
  float* Mp   = (float*)(ws + off); off += (size_t)32 * 8 * 4096 * 4;
  float* M    = (float*)(ws + off); off += (size_t)8 * 4096 * 4;
  u16*   Wg   = (u16*)(ws + off);   off += (size_t)9 * 128 * 128 * 2;
  float* shb  = (float*)(ws + off); off += 128 * 4;

  kv_proj<<<dim3(64, 8), 256, 0, stream>>>(x_skip, kv1_w, kv1_b, kv2_w, kv2_b,
                                           Knm, Vcm, K2t, V2t,
                                           conv_w, bn_g, bn_b, bn_m, bn_v, Wg, shb);
  attn_mfma<<<dim3(64, 8), 256, 0, stream>>>(x_up, x_skip, (const u16*)Knm, Vcm, xcat);
  chan_gram<<<dim3(32, 8), 256, 0, stream>>>(x_up, K2t, Mp);
  chan_reduce<<<128, 256, 0, stream>>>(Mp, M);
  chan_apply<<<dim3(64, 8), 256, 0, stream>>>(V2t, M, x_up, x_skip, xcat);
  conv_mfma<<<dim3(32, 8), 512, 0, stream>>>(xcat, Wg, shb, out);
}